// Round 4
// baseline (2448.949 us; speedup 1.0000x reference)
//
#include <hip/hip_runtime.h>
#include <hip/hip_bf16.h>

// ---------------------------------------------------------------------------
// Discriminator (HouseGAN-style). fp32 compute, bf16 activation storage.
// KEY FIX (r4): integer inputs (edges, nd_to_sample) arrive as int32 per the
// harness contract ("integer -> const int*"); reading them as int64 caused the
// page-fault aborts of rounds 1-3.
// Workspace: adaptive ping-pong, 2 regions x 64KiB/node, chunked over whole
// graphs if ws_size is small. Un-chunked needs 129 MiB.
// ---------------------------------------------------------------------------

#define N_NODES   1024
#define N_GRAPHS  64

typedef __hip_bfloat16 bf16;

__device__ __forceinline__ float cvt_in(float v) { return v; }
__device__ __forceinline__ float cvt_in(bf16 v)  { return __bfloat162float(v); }
__device__ __forceinline__ void  st_out(float* p, float v) { *p = v; }
__device__ __forceinline__ void  st_out(bf16*  p, float v) { *p = __float2bfloat16(v); }

// ---------------- deterministic adjacency build (no atomics) ---------------
// One thread per node scans its graph's contiguous 3-int edge records.
__global__ __launch_bounds__(64) void k_build_adj(
    const int* __restrict__ edges, int per_g,
    int* __restrict__ cnt, int* __restrict__ lst)
{
    int n = blockIdx.x * 64 + threadIdx.x;
    if (n >= N_NODES) return;
    int g = n >> 4;
    const int* eg = edges + (size_t)g * per_g * 3;
    int c = 0;
    for (int k = 0; k < per_g; ++k) {
        int a = eg[k * 3 + 0];
        int s = eg[k * 3 + 1];
        int b = eg[k * 3 + 2];
        int other = (a == n) ? b : ((b == n) ? a : -1);
        // same-graph guard: protects against any index surprise (no faults)
        if (other >= 0 && (other >> 4) == g && c < 16) {
            lst[n * 16 + c] = other | ((s < 0) ? (int)0x80000000 : 0);
            ++c;
        }
    }
    cnt[n] = c;
}

// ---------------- embed: h0[nl] = concat(x[n], (t@w_t.T+b_t) as 8ch) -------
__global__ __launch_bounds__(256) void k_embed(
    const float* __restrict__ x, const float* __restrict__ t,
    const float* __restrict__ wt, const float* __restrict__ bt,
    bf16* __restrict__ out, int node_base)
{
    int nl = blockIdx.x, n = node_base + nl, tid = threadIdx.x;
    __shared__ float tl[10];
    if (tid < 10) tl[tid] = t[n * 10 + tid];
    __syncthreads();
    for (int idx = tid; idx < 9 * 1024; idx += 256) {
        float v;
        if (idx < 1024) {
            v = x[(size_t)n * 1024 + idx];
        } else {
            int o = idx - 1024;
            float a = bt[o];
            const float* wr = wt + (size_t)o * 10;
            #pragma unroll
            for (int k = 0; k < 10; ++k) a += wr[k] * tl[k];
            v = a;
        }
        out[(size_t)nl * 9216 + idx] = __float2bfloat16(v);
    }
}

// ---------------- tiled 3x3 conv, pad 1 (chunk-local in/out) ---------------
template<int HIN, int STRIDE, int RELU, int CPG, typename TIN, typename TOUT>
__global__ __launch_bounds__(256) void k_conv(
    const TIN* __restrict__ in, const float* __restrict__ wgt,
    const float* __restrict__ bias, TOUT* __restrict__ out,
    int Cin, int Cout)
{
    constexpr int WIN  = HIN;
    constexpr int HOUT = (HIN - 1) / STRIDE + 1;
    constexpr int WOUT = HOUT;
    constexpr int NPIX = HOUT * WOUT;
    constexpr int P    = (NPIX + 255) / 256;
    constexpr int TW   = WIN + 2;
    __shared__ float stile[(HIN + 2) * TW];

    const int nl  = blockIdx.x;
    const int cob = blockIdx.y;
    const int tid = threadIdx.x;

    float acc[CPG][P];
    #pragma unroll
    for (int c = 0; c < CPG; ++c)
        #pragma unroll
        for (int p = 0; p < P; ++p) acc[c][p] = 0.f;

    const TIN*   inn = in + (size_t)nl * Cin * HIN * WIN;
    const float* wb  = wgt + (size_t)(cob * CPG) * Cin * 9;

    for (int ci = 0; ci < Cin; ++ci) {
        __syncthreads();
        const TIN* ic = inn + (size_t)ci * HIN * WIN;
        for (int i = tid; i < TW * TW; i += 256) {
            int gy = i / TW - 1, gx = i % TW - 1;
            float v = 0.f;
            if (gy >= 0 && gy < HIN && gx >= 0 && gx < WIN) v = cvt_in(ic[gy * WIN + gx]);
            stile[i] = v;
        }
        __syncthreads();

        float v[P][9];
        #pragma unroll
        for (int p = 0; p < P; ++p) {
            int pi  = tid + p * 256;
            int cpi = (pi < NPIX) ? pi : 0;
            int oy = cpi / WOUT, ox = cpi % WOUT;
            int b0 = oy * STRIDE * TW + ox * STRIDE;
            #pragma unroll
            for (int k = 0; k < 9; ++k)
                v[p][k] = stile[b0 + (k / 3) * TW + (k % 3)];
        }
        #pragma unroll
        for (int c = 0; c < CPG; ++c) {
            const float* wr = wb + (size_t)(c * Cin + ci) * 9;  // uniform -> s_load
            float w9[9];
            #pragma unroll
            for (int k = 0; k < 9; ++k) w9[k] = wr[k];
            #pragma unroll
            for (int p = 0; p < P; ++p)
                #pragma unroll
                for (int k = 0; k < 9; ++k)
                    acc[c][p] += w9[k] * v[p][k];
        }
    }

    #pragma unroll
    for (int c = 0; c < CPG; ++c) {
        int co = cob * CPG + c;
        float bv = bias[co];
        #pragma unroll
        for (int p = 0; p < P; ++p) {
            int pi = tid + p * 256;
            if (pi < NPIX) {
                float r = acc[c][p] + bv;
                if (RELU) r = (r >= 0.f) ? r : 0.1f * r;
                st_out(&out[((size_t)nl * Cout + co) * NPIX + pi], r);
            }
        }
    }
}

// ---------------- fused MPN-gather + 3x3 conv (Cin = 48 = self|pos|neg) ----
template<int HIN, int CPG>
__global__ __launch_bounds__(256) void k_conv_mpn(
    const bf16* __restrict__ in, const int* __restrict__ cnt,
    const int* __restrict__ lst, const float* __restrict__ wgt,
    const float* __restrict__ bias, bf16* __restrict__ out,
    int Cout, int node_base)
{
    constexpr int WIN   = HIN;
    constexpr int NPIXI = HIN * WIN;
    constexpr int NPIX  = NPIXI;
    constexpr int P     = (NPIX + 255) / 256;
    constexpr int TW    = WIN + 2;
    constexpr int NT    = TW * TW;
    constexpr int PC    = (NT + 255) / 256;

    __shared__ float stile[NT];
    __shared__ int   s_adj[16];
    __shared__ int   s_cnt;

    const int nl  = blockIdx.x;
    const int gn  = node_base + nl;
    const int cob = blockIdx.y;
    const int tid = threadIdx.x;

    if (tid == 0) { int c = cnt[gn]; s_cnt = (c > 16) ? 16 : c; }
    if (tid < 16) s_adj[tid] = lst[gn * 16 + tid];

    int  pix_[PC];
    bool val_[PC];
    #pragma unroll
    for (int p = 0; p < PC; ++p) {
        int i  = tid + p * 256;
        int gy = i / TW - 1, gx = i % TW - 1;
        bool ok = (i < NT) && gy >= 0 && gy < HIN && gx >= 0 && gx < WIN;
        val_[p] = ok;
        pix_[p] = ok ? (gy * WIN + gx) : 0;
    }

    float acc[CPG][P];
    #pragma unroll
    for (int c = 0; c < CPG; ++c)
        #pragma unroll
        for (int p = 0; p < P; ++p) acc[c][p] = 0.f;

    const float* wb = wgt + (size_t)(cob * CPG) * 48 * 9;
    __syncthreads();

    for (int ci = 0; ci < 48; ++ci) {
        __syncthreads();
        int ch = ci & 15;
        float v[PC];
        #pragma unroll
        for (int p = 0; p < PC; ++p) v[p] = 0.f;

        if (ci < 16) {
            const bf16* base = in + ((size_t)nl * 16 + ch) * NPIXI;
            #pragma unroll
            for (int p = 0; p < PC; ++p) v[p] = __bfloat162float(base[pix_[p]]);
        } else {
            bool wantneg = (ci >= 32);
            int  c = s_cnt;
            for (int k = 0; k < c; ++k) {
                int e = s_adj[k];                        // wave-uniform
                if ((e < 0) == wantneg) {
                    int src_l = (e & 0x7FFFFFFF) - node_base;  // same graph -> in chunk
                    const bf16* base = in + ((size_t)src_l * 16 + ch) * NPIXI;
                    #pragma unroll
                    for (int p = 0; p < PC; ++p) v[p] += __bfloat162float(base[pix_[p]]);
                }
            }
        }
        #pragma unroll
        for (int p = 0; p < PC; ++p) {
            int i = tid + p * 256;
            if (i < NT) stile[i] = val_[p] ? v[p] : 0.f;
        }
        __syncthreads();

        float vv[P][9];
        #pragma unroll
        for (int p = 0; p < P; ++p) {
            int pi = tid + p * 256;
            int oy = pi / WIN, ox = pi % WIN;
            int b0 = oy * TW + ox;
            #pragma unroll
            for (int k = 0; k < 9; ++k)
                vv[p][k] = stile[b0 + (k / 3) * TW + (k % 3)];
        }
        #pragma unroll
        for (int c = 0; c < CPG; ++c) {
            const float* wr = wb + (size_t)(c * 48 + ci) * 9;
            float w9[9];
            #pragma unroll
            for (int k = 0; k < 9; ++k) w9[k] = wr[k];
            #pragma unroll
            for (int p = 0; p < P; ++p)
                #pragma unroll
                for (int k = 0; k < 9; ++k)
                    acc[c][p] += w9[k] * vv[p][k];
        }
    }

    #pragma unroll
    for (int c = 0; c < CPG; ++c) {
        int co = cob * CPG + c;
        float bv = bias[co];
        #pragma unroll
        for (int p = 0; p < P; ++p) {
            int pi = tid + p * 256;
            if (pi < NPIX)
                out[((size_t)nl * Cout + co) * NPIX + pi] =
                    __float2bfloat16(acc[c][p] + bv);
        }
    }
}

// ---------------- small-spatial direct conv (d1/d2/d3), always lrelu -------
template<int HIN, int STRIDE, int CIN>
__global__ __launch_bounds__(256) void k_conv_small(
    const float* __restrict__ in, const float* __restrict__ wgt,
    const float* __restrict__ bias, float* __restrict__ out, int Cout)
{
    constexpr int HOUT = (HIN - 1) / STRIDE + 1;
    constexpr int NPIX = HOUT * HOUT;
    __shared__ float sin_[CIN * HIN * HIN];
    int nl = blockIdx.x, tid = threadIdx.x;
    const float* inn = in + (size_t)nl * CIN * HIN * HIN;
    for (int i = tid; i < CIN * HIN * HIN; i += 256) sin_[i] = inn[i];
    __syncthreads();
    int total = Cout * NPIX;
    for (int o = tid; o < total; o += 256) {
        int co = o / NPIX, pi = o % NPIX;
        int oy = pi / HOUT, ox = pi % HOUT;
        float a = bias[co];
        const float* wr = wgt + (size_t)co * CIN * 9;
        for (int ci = 0; ci < CIN; ++ci) {
            #pragma unroll
            for (int ky = 0; ky < 3; ++ky) {
                int iy = oy * STRIDE + ky - 1;
                if (iy < 0 || iy >= HIN) continue;
                #pragma unroll
                for (int kx = 0; kx < 3; ++kx) {
                    int ix = ox * STRIDE + kx - 1;
                    if (ix < 0 || ix >= HIN) continue;
                    a += sin_[(ci * HIN + iy) * HIN + ix] * wr[ci * 9 + ky * 3 + kx];
                }
            }
        }
        a = (a >= 0.f) ? a : 0.1f * a;
        out[(size_t)nl * total + o] = a;
    }
}

// ---------------- head ------------------------------------------------------
__global__ void k_init_out(float* out, const float* __restrict__ pb)
{
    int i = threadIdx.x;
    if (i < N_GRAPHS) out[i] = pb[0];
}

__global__ __launch_bounds__(64) void k_pool(
    const float* __restrict__ h, const int* __restrict__ nd,
    const float* __restrict__ pw, float* out, int node_base)
{
    int nl = blockIdx.x, tid = threadIdx.x;
    float a = h[(size_t)nl * 128 + tid] * pw[tid]
            + h[(size_t)nl * 128 + 64 + tid] * pw[64 + tid];
    #pragma unroll
    for (int off = 32; off > 0; off >>= 1)
        a += __shfl_down(a, off, 64);
    if (tid == 0) {
        int g = nd[node_base + nl];
        if (g < 0) g = 0; if (g >= N_GRAPHS) g = N_GRAPHS - 1;   // no-fault guard
        atomicAdd(&out[g], a);
    }
}

// ---------------------------------------------------------------------------
extern "C" void kernel_launch(void* const* d_in, const int* in_sizes, int n_in,
                              void* d_out, int out_size, void* d_ws, size_t ws_size,
                              hipStream_t stream)
{
    const float* x     = (const float*)d_in[0];
    const float* t     = (const float*)d_in[1];
    const int*   edges = (const int*)d_in[2];      // int32 per harness contract
    const int*   nd    = (const int*)d_in[3];      // int32 per harness contract
    const float* w_t   = (const float*)d_in[4];
    const float* b_t   = (const float*)d_in[5];
    const float* c1w   = (const float*)d_in[6];
    const float* c1b   = (const float*)d_in[7];
    const float* c2w   = (const float*)d_in[8];
    const float* c2b   = (const float*)d_in[9];
    const float* c3w   = (const float*)d_in[10];
    const float* c3b   = (const float*)d_in[11];
    const float* m1c1w = (const float*)d_in[12];
    const float* m1c1b = (const float*)d_in[13];
    const float* m1c2w = (const float*)d_in[14];
    const float* m1c2b = (const float*)d_in[15];
    const float* m1c3w = (const float*)d_in[16];
    const float* m1c3b = (const float*)d_in[17];
    const float* ds1w  = (const float*)d_in[18];
    const float* ds1b  = (const float*)d_in[19];
    const float* m2c1w = (const float*)d_in[20];
    const float* m2c1b = (const float*)d_in[21];
    const float* m2c2w = (const float*)d_in[22];
    const float* m2c2b = (const float*)d_in[23];
    const float* m2c3w = (const float*)d_in[24];
    const float* m2c3b = (const float*)d_in[25];
    const float* ds2w  = (const float*)d_in[26];
    const float* ds2b  = (const float*)d_in[27];
    const float* d1w   = (const float*)d_in[28];
    const float* d1b   = (const float*)d_in[29];
    const float* d2w   = (const float*)d_in[30];
    const float* d2b   = (const float*)d_in[31];
    const float* d3w   = (const float*)d_in[32];
    const float* d3b   = (const float*)d_in[33];
    const float* pw    = (const float*)d_in[34];
    const float* pb    = (const float*)d_in[35];
    float* out = (float*)d_out;

    uint8_t* ws = (uint8_t*)d_ws;
    int* adj_cnt = (int*)ws;               // [0, 4K)
    int* adj_lst = (int*)(ws + 4096);      // [4K, 68K)

    // ---- adaptive chunking: ping-pong regions A/B, 64 KiB per node each ----
    const size_t RESV = 1ull << 20;                 // adjacency + slack
    size_t avail = (ws_size > RESV) ? ws_size - RESV : 0;
    int ncap = (int)(avail / (2 * 65536));          // nodes per chunk capacity
    ncap = (ncap / 16) * 16;                        // whole graphs
    if (ncap < 16)  ncap = 16;                      // last resort
    if (ncap > N_NODES) ncap = N_NODES;

    uint8_t* regA = ws + RESV;
    uint8_t* regB = regA + (size_t)ncap * 65536;

    bf16*  h0    = (bf16*)regA;
    bf16*  c1o   = (bf16*)regB;
    bf16*  c2o   = (bf16*)regA;
    bf16*  c3o   = (bf16*)regB;
    bf16*  m1c1o = (bf16*)regA;
    bf16*  m1c2o = (bf16*)regB;
    bf16*  m1c3o = (bf16*)regA;
    bf16*  ds1o  = (bf16*)regB;
    bf16*  m2c1o = (bf16*)regA;
    bf16*  m2c2o = (bf16*)regB;
    bf16*  m2c3o = (bf16*)regA;
    float* ds2o  = (float*)regB;
    float* d1o   = (float*)regA;
    float* d2o   = (float*)regB;
    float* d3o   = (float*)regA;

    int nE    = in_sizes[2] / 3;
    int per_g = nE / N_GRAPHS;

    k_build_adj<<<(N_NODES + 63) / 64, 64, 0, stream>>>(edges, per_g, adj_cnt, adj_lst);
    k_init_out<<<1, 64, 0, stream>>>(out, pb);

    for (int nb = 0; nb < N_NODES; nb += ncap) {
        int nc = (N_NODES - nb < ncap) ? (N_NODES - nb) : ncap;

        k_embed<<<nc, 256, 0, stream>>>(x, t, w_t, b_t, h0, nb);

        k_conv<32,1,1,8,bf16,bf16><<<dim3(nc,2), 256, 0, stream>>>(h0,  c1w, c1b, c1o, 9, 16);
        k_conv<32,1,1,8,bf16,bf16><<<dim3(nc,2), 256, 0, stream>>>(c1o, c2w, c2b, c2o, 16, 16);
        k_conv<32,1,1,8,bf16,bf16><<<dim3(nc,2), 256, 0, stream>>>(c2o, c3w, c3b, c3o, 16, 16);

        k_conv_mpn<32,16><<<dim3(nc,2), 256, 0, stream>>>(c3o, adj_cnt, adj_lst,
                                                          m1c1w, m1c1b, m1c1o, 32, nb);
        k_conv<32,1,0,16,bf16,bf16><<<dim3(nc,2), 256, 0, stream>>>(m1c1o, m1c2w, m1c2b, m1c2o, 32, 32);
        k_conv<32,1,0,8,bf16,bf16><<<dim3(nc,2), 256, 0, stream>>>(m1c2o, m1c3w, m1c3b, m1c3o, 32, 16);

        k_conv<32,2,1,8,bf16,bf16><<<dim3(nc,2), 256, 0, stream>>>(m1c3o, ds1w, ds1b, ds1o, 16, 16);

        k_conv_mpn<16,16><<<dim3(nc,2), 256, 0, stream>>>(ds1o, adj_cnt, adj_lst,
                                                          m2c1w, m2c1b, m2c1o, 32, nb);
        k_conv<16,1,0,16,bf16,bf16><<<dim3(nc,2), 256, 0, stream>>>(m2c1o, m2c2w, m2c2b, m2c2o, 32, 32);
        k_conv<16,1,0,8,bf16,bf16><<<dim3(nc,2), 256, 0, stream>>>(m2c2o, m2c3w, m2c3b, m2c3o, 32, 16);

        k_conv<16,2,1,8,bf16,float><<<dim3(nc,2), 256, 0, stream>>>(m2c3o, ds2w, ds2b, ds2o, 16, 16);

        k_conv_small<8,2,16>  <<<nc, 256, 0, stream>>>(ds2o, d1w, d1b, d1o, 256);
        k_conv_small<4,2,256> <<<nc, 256, 0, stream>>>(d1o,  d2w, d2b, d2o, 128);
        k_conv_small<2,2,128> <<<nc, 256, 0, stream>>>(d2o,  d3w, d3b, d3o, 128);

        k_pool<<<nc, 64, 0, stream>>>(d3o, nd, pw, out, nb);
    }
}

// Round 5
// 1120.142 us; speedup vs baseline: 2.1863x; 2.1863x over previous
//
#include <hip/hip_runtime.h>
#include <hip/hip_bf16.h>

// ---------------------------------------------------------------------------
// Discriminator (HouseGAN-style), MFMA implicit-GEMM version.
// Activations: grouped-HWC bf16  [n][ci/8][px][8ci]  (16B chunks per px).
// Convs (3x3, pad 1, stride 1) run as mfma_f32_32x32x16_bf16:
//   A = weights (M=Cout rows, pre-packed per-lane fragments in ws)
//   B = pixels  (N=32 px via contiguous ds_read_b128 from grouped-HWC LDS)
//   K = 16 input channels per phase (Cin staged 16-at-a-time, 32KB LDS).
// ---------------------------------------------------------------------------

#define N_NODES   1024
#define N_GRAPHS  64

typedef __hip_bfloat16 bf16;
typedef __attribute__((ext_vector_type(8)))  short  short8;
typedef __attribute__((ext_vector_type(16))) float  f32x16;

__device__ __forceinline__ float bf2f(unsigned short s) {
    union { unsigned u; float f; } x; x.u = ((unsigned)s) << 16; return x.f;
}
__device__ __forceinline__ unsigned short f2bf(float f) {
    __hip_bfloat16 h = __float2bfloat16(f);
    return *reinterpret_cast<unsigned short*>(&h);
}
__device__ __forceinline__ uint4 pack8(const float* f) {
    uint4 r;
    r.x = f2bf(f[0]) | ((unsigned)f2bf(f[1]) << 16);
    r.y = f2bf(f[2]) | ((unsigned)f2bf(f[3]) << 16);
    r.z = f2bf(f[4]) | ((unsigned)f2bf(f[5]) << 16);
    r.w = f2bf(f[6]) | ((unsigned)f2bf(f[7]) << 16);
    return r;
}

// ---------------- deterministic adjacency build ----------------------------
__global__ __launch_bounds__(64) void k_build_adj(
    const int* __restrict__ edges, int per_g,
    int* __restrict__ cnt, int* __restrict__ lst)
{
    int n = blockIdx.x * 64 + threadIdx.x;
    if (n >= N_NODES) return;
    int g = n >> 4;
    const int* eg = edges + (size_t)g * per_g * 3;
    int c = 0;
    for (int k = 0; k < per_g; ++k) {
        int a = eg[k * 3 + 0];
        int s = eg[k * 3 + 1];
        int b = eg[k * 3 + 2];
        int other = (a == n) ? b : ((b == n) ? a : -1);
        if (other >= 0 && (other >> 4) == g && c < 16) {
            lst[n * 16 + c] = other | ((s < 0) ? (int)0x80000000 : 0);
            ++c;
        }
    }
    cnt[n] = c;
}

// ---------------- weight fragment pre-pack ---------------------------------
// wf[kk][cig16][lane][8]: lane: co=lane&31, k-half=lane>>5; elem j -> ci =
// cig*16 + (lane>>5)*8 + j. Zero-padded for co>=Cout or ci>=Cin.
__global__ __launch_bounds__(64) void k_prep_w(
    const float* __restrict__ w, unsigned short* __restrict__ wf,
    int Cin, int Cout)
{
    int kk = blockIdx.x, cg = blockIdx.y, ncg = gridDim.y;
    int lane = threadIdx.x;
    int co = lane & 31, kg = lane >> 5;
    float v[8];
    #pragma unroll
    for (int j = 0; j < 8; ++j) {
        int ci = cg * 16 + kg * 8 + j;
        v[j] = (co < Cout && ci < Cin) ? w[((size_t)co * Cin + ci) * 9 + kk] : 0.f;
    }
    *(uint4*)(wf + ((size_t)(kk * ncg + cg) * 64 + lane) * 8) = pack8(v);
}

// ---------------- embed -> grouped-HWC [nc][2][1024][8], ch9..15 zero ------
__global__ __launch_bounds__(256) void k_embed(
    const float* __restrict__ x, const float* __restrict__ t,
    const float* __restrict__ wt, const float* __restrict__ bt,
    bf16* __restrict__ out, int node_base)
{
    int nl = blockIdx.x, n = node_base + nl, tid = threadIdx.x;
    __shared__ float tl[10];
    if (tid < 10) tl[tid] = t[n * 10 + tid];
    __syncthreads();
    uint4* o4 = (uint4*)out;
    for (int p = 0; p < 4; ++p) {
        int px = tid + p * 256;
        float ch[16];
        ch[0] = x[(size_t)n * 1024 + px];
        #pragma unroll
        for (int c = 1; c <= 8; ++c) {
            int o = (c - 1) * 1024 + px;
            float a = bt[o];
            const float* wr = wt + (size_t)o * 10;
            #pragma unroll
            for (int k = 0; k < 10; ++k) a += wr[k] * tl[k];
            ch[c] = a;
        }
        #pragma unroll
        for (int c = 9; c < 16; ++c) ch[c] = 0.f;
        o4[(size_t)(nl * 2 + 0) * 1024 + px] = pack8(ch);
        o4[(size_t)(nl * 2 + 1) * 1024 + px] = pack8(ch + 8);
    }
}

// ---------------- MFMA conv 3x3 pad1 stride1 -------------------------------
template<int NPIX, int CIG16, int COUT, int RELU>
__global__ __launch_bounds__(256) void k_conv_mfma(
    const bf16* __restrict__ in, const unsigned short* __restrict__ wf,
    const float* __restrict__ bias, bf16* __restrict__ out)
{
    constexpr int W   = (NPIX == 1024) ? 32 : 16;
    constexpr int TPW = NPIX / 128;          // output 32-px tiles per wave
    __shared__ __align__(16) short sbuf[2 * NPIX * 8 + 8];
    __shared__ float sbias[32];

    const int n   = blockIdx.x;
    const int tid = threadIdx.x;
    const int wid = tid >> 6, lane = tid & 63;
    const int pxl = lane & 31, kg = lane >> 5;

    if (tid < 8)  sbuf[2 * NPIX * 8 + tid] = 0;       // zero slot
    if (tid < 32) sbias[tid] = (tid < COUT) ? bias[tid] : 0.f;

    f32x16 acc[TPW];
    #pragma unroll
    for (int tt = 0; tt < TPW; ++tt)
        #pragma unroll
        for (int e = 0; e < 16; ++e) acc[tt][e] = 0.f;

    for (int ph = 0; ph < CIG16; ++ph) {
        __syncthreads();
        const uint4* src = (const uint4*)in + ((size_t)n * CIG16 + ph) * 2 * NPIX;
        uint4* dst = (uint4*)sbuf;
        for (int i = tid; i < 2 * NPIX; i += 256) dst[i] = src[i];
        __syncthreads();

        short8 wfr[9];
        #pragma unroll
        for (int kk = 0; kk < 9; ++kk)
            wfr[kk] = *(const short8*)(wf + ((size_t)(kk * CIG16 + ph) * 64 + lane) * 8);

        #pragma unroll
        for (int tt = 0; tt < TPW; ++tt) {
            int tile = wid * TPW + tt;
            int oy = (W == 32) ? tile : (tile * 2 + (pxl >> 4));
            int ox = (W == 32) ? pxl  : (pxl & 15);
            #pragma unroll
            for (int kk = 0; kk < 9; ++kk) {
                const int dy = kk / 3 - 1, dx = kk % 3 - 1;
                int iy = oy + dy, ix = ox + dx;
                bool ok = ((unsigned)iy < (unsigned)W) && ((unsigned)ix < (unsigned)W);
                int chunk = ok ? (kg * NPIX + iy * W + ix) : (2 * NPIX);
                const short8* bp = (const short8*)(sbuf + chunk * 8);
                acc[tt] = __builtin_amdgcn_mfma_f32_32x32x16_bf16(wfr[kk], *bp, acc[tt], 0, 0, 0);
            }
        }
    }

    // epilogue: coalesced 8B stores in grouped-HWC
    unsigned short* outp = (unsigned short*)out;
    #pragma unroll
    for (int tt = 0; tt < TPW; ++tt) {
        int tile = wid * TPW + tt;
        int oy = (W == 32) ? tile : (tile * 2 + (pxl >> 4));
        int ox = (W == 32) ? pxl  : (pxl & 15);
        int opx = oy * W + ox;
        #pragma unroll
        for (int q = 0; q < COUT / 8; ++q) {
            unsigned short u[4];
            #pragma unroll
            for (int j = 0; j < 4; ++j) {
                int co = q * 8 + kg * 4 + j;
                float v = acc[tt][4 * q + j] + sbias[co];
                if (RELU) v = (v >= 0.f) ? v : 0.1f * v;
                u[j] = f2bf(v);
            }
            uint2 pk;
            pk.x = u[0] | ((unsigned)u[1] << 16);
            pk.y = u[2] | ((unsigned)u[3] << 16);
            *(uint2*)(outp + ((size_t)(n * (COUT / 8) + q) * NPIX + opx) * 8 + kg * 4) = pk;
        }
    }
}

// ---------------- MPN gather: [self | pos-sum | neg-sum], grouped-HWC ------
template<int NPIX>
__global__ __launch_bounds__(256) void k_gather(
    const bf16* __restrict__ in, const int* __restrict__ cnt,
    const int* __restrict__ lst, bf16* __restrict__ out, int node_base)
{
    constexpr int CPN = 2 * NPIX;            // 16B chunks per node (16 ch)
    const int gl = blockIdx.x, split = blockIdx.y, tid = threadIdx.x;
    const int gn0 = node_base + gl * 16;
    const int nl0 = gl * 16;
    __shared__ int s_adj[16][16];
    __shared__ int s_cnt[16];
    if (tid < 16) s_cnt[tid] = cnt[gn0 + tid];
    s_adj[tid >> 4][tid & 15] = lst[(size_t)(gn0 + (tid >> 4)) * 16 + (tid & 15)];
    __syncthreads();

    int pos = split * 256 + tid;
    const uint4* in4 = (const uint4*)in;
    uint4* out4 = (uint4*)out;

    for (int l = 0; l < 16; ++l) {
        int nl = nl0 + l;
        uint4 self = in4[(size_t)nl * CPN + pos];
        float P[8], Nn[8];
        #pragma unroll
        for (int j = 0; j < 8; ++j) { P[j] = 0.f; Nn[j] = 0.f; }
        int c = s_cnt[l];
        for (int k = 0; k < c; ++k) {
            int e = s_adj[l][k];                       // wave-uniform
            int sl = (e & 0x7FFFFFFF) - node_base;
            union { uint4 v; unsigned short s[8]; } u;
            u.v = in4[(size_t)sl * CPN + pos];
            if (e < 0) {
                #pragma unroll
                for (int j = 0; j < 8; ++j) Nn[j] += bf2f(u.s[j]);
            } else {
                #pragma unroll
                for (int j = 0; j < 8; ++j) P[j] += bf2f(u.s[j]);
            }
        }
        size_t ob = (size_t)nl * 3 * CPN + pos;
        out4[ob]            = self;
        out4[ob + CPN]      = pack8(P);
        out4[ob + 2 * CPN]  = pack8(Nn);
    }
}

// ---------------- scalar stride-2 conv on grouped input --------------------
// GOUT=1: write grouped bf16; GOUT=0: write fp32 NCHW. Cin=Cout=16, lrelu.
template<int HIN, int GOUT>
__global__ __launch_bounds__(256) void k_conv_s2g(
    const bf16* __restrict__ in, const float* __restrict__ wgt,
    const float* __restrict__ bias, void* __restrict__ outv)
{
    constexpr int HOUT = HIN / 2, NPO = HOUT * HOUT;
    const int n = blockIdx.x, tid = threadIdx.x;
    if (tid >= NPO) return;
    int oy = tid / HOUT, ox = tid % HOUT;
    float acc[16];
    #pragma unroll
    for (int co = 0; co < 16; ++co) acc[co] = bias[co];
    const uint4* in4 = (const uint4*)in + (size_t)n * 2 * HIN * HIN;
    #pragma unroll
    for (int kk = 0; kk < 9; ++kk) {
        int iy = 2 * oy + kk / 3 - 1, ix = 2 * ox + kk % 3 - 1;
        if ((unsigned)iy >= (unsigned)HIN || (unsigned)ix >= (unsigned)HIN) continue;
        #pragma unroll
        for (int cg = 0; cg < 2; ++cg) {
            union { uint4 v; unsigned short s[8]; } u;
            u.v = in4[cg * HIN * HIN + iy * HIN + ix];
            #pragma unroll
            for (int ci = 0; ci < 8; ++ci) {
                float f = bf2f(u.s[ci]);
                #pragma unroll
                for (int co = 0; co < 16; ++co)
                    acc[co] += f * wgt[((size_t)co * 16 + cg * 8 + ci) * 9 + kk];
            }
        }
    }
    #pragma unroll
    for (int co = 0; co < 16; ++co)
        acc[co] = (acc[co] >= 0.f) ? acc[co] : 0.1f * acc[co];
    if (GOUT) {
        uint4* o4 = (uint4*)outv;
        o4[(size_t)(n * 2 + 0) * NPO + tid] = pack8(acc);
        o4[(size_t)(n * 2 + 1) * NPO + tid] = pack8(acc + 8);
    } else {
        float* o = (float*)outv;
        #pragma unroll
        for (int co = 0; co < 16; ++co)
            o[((size_t)n * 16 + co) * NPO + tid] = acc[co];
    }
}

// ---------------- small-spatial direct conv (d1/d2/d3), fp32 NCHW ----------
template<int HIN, int STRIDE, int CIN>
__global__ __launch_bounds__(256) void k_conv_small(
    const float* __restrict__ in, const float* __restrict__ wgt,
    const float* __restrict__ bias, float* __restrict__ out, int Cout)
{
    constexpr int HOUT = (HIN - 1) / STRIDE + 1;
    constexpr int NPIX = HOUT * HOUT;
    __shared__ float sin_[CIN * HIN * HIN];
    int nl = blockIdx.x, tid = threadIdx.x;
    const float* inn = in + (size_t)nl * CIN * HIN * HIN;
    for (int i = tid; i < CIN * HIN * HIN; i += 256) sin_[i] = inn[i];
    __syncthreads();
    int total = Cout * NPIX;
    for (int o = tid; o < total; o += 256) {
        int co = o / NPIX, pi = o % NPIX;
        int oy = pi / HOUT, ox = pi % HOUT;
        float a = bias[co];
        const float* wr = wgt + (size_t)co * CIN * 9;
        for (int ci = 0; ci < CIN; ++ci) {
            #pragma unroll
            for (int ky = 0; ky < 3; ++ky) {
                int iy = oy * STRIDE + ky - 1;
                if (iy < 0 || iy >= HIN) continue;
                #pragma unroll
                for (int kx = 0; kx < 3; ++kx) {
                    int ix = ox * STRIDE + kx - 1;
                    if (ix < 0 || ix >= HIN) continue;
                    a += sin_[(ci * HIN + iy) * HIN + ix] * wr[ci * 9 + ky * 3 + kx];
                }
            }
        }
        a = (a >= 0.f) ? a : 0.1f * a;
        out[(size_t)nl * total + o] = a;
    }
}

// ---------------- head ------------------------------------------------------
__global__ void k_init_out(float* out, const float* __restrict__ pb)
{
    int i = threadIdx.x;
    if (i < N_GRAPHS) out[i] = pb[0];
}

__global__ __launch_bounds__(64) void k_pool(
    const float* __restrict__ h, const int* __restrict__ nd,
    const float* __restrict__ pw, float* out, int node_base)
{
    int nl = blockIdx.x, tid = threadIdx.x;
    float a = h[(size_t)nl * 128 + tid] * pw[tid]
            + h[(size_t)nl * 128 + 64 + tid] * pw[64 + tid];
    #pragma unroll
    for (int off = 32; off > 0; off >>= 1)
        a += __shfl_down(a, off, 64);
    if (tid == 0) {
        int g = nd[node_base + nl];
        if (g < 0) g = 0; if (g >= N_GRAPHS) g = N_GRAPHS - 1;
        atomicAdd(&out[g], a);
    }
}

// ---------------------------------------------------------------------------
extern "C" void kernel_launch(void* const* d_in, const int* in_sizes, int n_in,
                              void* d_out, int out_size, void* d_ws, size_t ws_size,
                              hipStream_t stream)
{
    const float* x     = (const float*)d_in[0];
    const float* t     = (const float*)d_in[1];
    const int*   edges = (const int*)d_in[2];
    const int*   nd    = (const int*)d_in[3];
    const float* w_t   = (const float*)d_in[4];
    const float* b_t   = (const float*)d_in[5];
    const float* c1w   = (const float*)d_in[6];
    const float* c1b   = (const float*)d_in[7];
    const float* c2w   = (const float*)d_in[8];
    const float* c2b   = (const float*)d_in[9];
    const float* c3w   = (const float*)d_in[10];
    const float* c3b   = (const float*)d_in[11];
    const float* m1c1w = (const float*)d_in[12];
    const float* m1c1b = (const float*)d_in[13];
    const float* m1c2w = (const float*)d_in[14];
    const float* m1c2b = (const float*)d_in[15];
    const float* m1c3w = (const float*)d_in[16];
    const float* m1c3b = (const float*)d_in[17];
    const float* ds1w  = (const float*)d_in[18];
    const float* ds1b  = (const float*)d_in[19];
    const float* m2c1w = (const float*)d_in[20];
    const float* m2c1b = (const float*)d_in[21];
    const float* m2c2w = (const float*)d_in[22];
    const float* m2c2b = (const float*)d_in[23];
    const float* m2c3w = (const float*)d_in[24];
    const float* m2c3b = (const float*)d_in[25];
    const float* ds2w  = (const float*)d_in[26];
    const float* ds2b  = (const float*)d_in[27];
    const float* d1w   = (const float*)d_in[28];
    const float* d1b   = (const float*)d_in[29];
    const float* d2w   = (const float*)d_in[30];
    const float* d2b   = (const float*)d_in[31];
    const float* d3w   = (const float*)d_in[32];
    const float* d3b   = (const float*)d_in[33];
    const float* pw    = (const float*)d_in[34];
    const float* pb    = (const float*)d_in[35];
    float* out = (float*)d_out;

    uint8_t* ws = (uint8_t*)d_ws;
    int* adj_cnt = (int*)ws;                         // [0, 4K)
    int* adj_lst = (int*)(ws + 4096);                // [4K, 68K)
    // weight-fragment slots: [128K, 128K + 9*32K)
    #define WF(i) ((unsigned short*)(ws + (128u << 10) + (size_t)(i) * 32768))

    // ---- adaptive chunking: liveness-packed pool, 160 KiB per node --------
    const size_t RESV = 1ull << 20;
    size_t avail = (ws_size > RESV) ? ws_size - RESV : 0;
    int ncap = (int)(avail / (160 * 1024));
    ncap = (ncap / 16) * 16;
    if (ncap < 16) ncap = 16;
    if (ncap > N_NODES) ncap = N_NODES;
    uint8_t* R = ws + RESV;
    #define NB(off_kb) (R + (size_t)(off_kb) * 1024 * ncap)

    bf16*  h0    = (bf16*)NB(0);      // [0,32)
    bf16*  c1o   = (bf16*)NB(32);     // [32,64)
    bf16*  c2o   = (bf16*)NB(64);     // [64,96)
    bf16*  c3o   = (bf16*)NB(128);    // [128,160)
    bf16*  g1    = (bf16*)NB(0);      // [0,96)
    bf16*  m1c1o = (bf16*)NB(96);     // [96,160)
    bf16*  m1c2o = (bf16*)NB(0);      // [0,64)
    bf16*  m1c3o = (bf16*)NB(64);     // [64,96)
    bf16*  ds1o  = (bf16*)NB(0);      // [0,8)
    bf16*  g2    = (bf16*)NB(8);      // [8,32)
    bf16*  m2c1o = (bf16*)NB(32);     // [32,48)
    bf16*  m2c2o = (bf16*)NB(0);      // [0,16)
    bf16*  m2c3o = (bf16*)NB(16);     // [16,24)
    float* ds2o  = (float*)NB(24);    // [24,28)
    float* d1o   = (float*)NB(0);     // [0,16)
    float* d2o   = (float*)NB(16);    // [16,18)
    float* d3o   = (float*)NB(18);    // [18,18.5)

    int nE    = in_sizes[2] / 3;
    int per_g = nE / N_GRAPHS;

    k_build_adj<<<(N_NODES + 63) / 64, 64, 0, stream>>>(edges, per_g, adj_cnt, adj_lst);
    k_init_out<<<1, 64, 0, stream>>>(out, pb);

    k_prep_w<<<dim3(9, 1), 64, 0, stream>>>(c1w,   WF(0), 9,  16);
    k_prep_w<<<dim3(9, 1), 64, 0, stream>>>(c2w,   WF(1), 16, 16);
    k_prep_w<<<dim3(9, 1), 64, 0, stream>>>(c3w,   WF(2), 16, 16);
    k_prep_w<<<dim3(9, 3), 64, 0, stream>>>(m1c1w, WF(3), 48, 32);
    k_prep_w<<<dim3(9, 2), 64, 0, stream>>>(m1c2w, WF(4), 32, 32);
    k_prep_w<<<dim3(9, 2), 64, 0, stream>>>(m1c3w, WF(5), 32, 16);
    k_prep_w<<<dim3(9, 3), 64, 0, stream>>>(m2c1w, WF(6), 48, 32);
    k_prep_w<<<dim3(9, 2), 64, 0, stream>>>(m2c2w, WF(7), 32, 32);
    k_prep_w<<<dim3(9, 2), 64, 0, stream>>>(m2c3w, WF(8), 32, 16);

    for (int nb = 0; nb < N_NODES; nb += ncap) {
        int nc = (N_NODES - nb < ncap) ? (N_NODES - nb) : ncap;
        int ng = nc / 16;

        k_embed<<<nc, 256, 0, stream>>>(x, t, w_t, b_t, h0, nb);

        k_conv_mfma<1024, 1, 16, 1><<<nc, 256, 0, stream>>>(h0,  WF(0), c1b, c1o);
        k_conv_mfma<1024, 1, 16, 1><<<nc, 256, 0, stream>>>(c1o, WF(1), c2b, c2o);
        k_conv_mfma<1024, 1, 16, 1><<<nc, 256, 0, stream>>>(c2o, WF(2), c3b, c3o);

        k_gather<1024><<<dim3(ng, 8), 256, 0, stream>>>(c3o, adj_cnt, adj_lst, g1, nb);
        k_conv_mfma<1024, 3, 32, 0><<<nc, 256, 0, stream>>>(g1,    WF(3), m1c1b, m1c1o);
        k_conv_mfma<1024, 2, 32, 0><<<nc, 256, 0, stream>>>(m1c1o, WF(4), m1c2b, m1c2o);
        k_conv_mfma<1024, 2, 16, 0><<<nc, 256, 0, stream>>>(m1c2o, WF(5), m1c3b, m1c3o);

        k_conv_s2g<32, 1><<<nc, 256, 0, stream>>>(m1c3o, ds1w, ds1b, (void*)ds1o);

        k_gather<256><<<dim3(ng, 2), 256, 0, stream>>>(ds1o, adj_cnt, adj_lst, g2, nb);
        k_conv_mfma<256, 3, 32, 0><<<nc, 256, 0, stream>>>(g2,    WF(6), m2c1b, m2c1o);
        k_conv_mfma<256, 2, 32, 0><<<nc, 256, 0, stream>>>(m2c1o, WF(7), m2c2b, m2c2o);
        k_conv_mfma<256, 2, 16, 0><<<nc, 256, 0, stream>>>(m2c2o, WF(8), m2c3b, m2c3o);

        k_conv_s2g<16, 0><<<nc, 64, 0, stream>>>(m2c3o, ds2w, ds2b, (void*)ds2o);

        k_conv_small<8, 2, 16>  <<<nc, 256, 0, stream>>>(ds2o, d1w, d1b, d1o, 256);
        k_conv_small<4, 2, 256> <<<nc, 256, 0, stream>>>(d1o,  d2w, d2b, d2o, 128);
        k_conv_small<2, 2, 128> <<<nc, 256, 0, stream>>>(d2o,  d3w, d3b, d3o, 128);

        k_pool<<<nc, 64, 0, stream>>>(d3o, nd, pw, out, nb);
    }
    #undef NB
    #undef WF
}

// Round 6
// 572.237 us; speedup vs baseline: 4.2796x; 1.9575x over previous
//
#include <hip/hip_runtime.h>
#include <hip/hip_bf16.h>

// ---------------------------------------------------------------------------
// Discriminator (HouseGAN-style), full-MFMA version.
// Activations: grouped-HWC bf16  [n][ci/8][px][8ci]  (16B chunks per px).
// Stride-1 convs: k_conv_mfma (per-image). Stride-2 tail convs: k_tail with
// images batched into the MFMA N dimension; d3 fuses the pooling head.
// MFMA fragment layouts (verified r5): A m=lane&31,k=(lane>>5)*8+j;
// B col=lane&31; C col=lane&31,row=(reg&3)+8*(reg>>2)+4*(lane>>5).
// ---------------------------------------------------------------------------

#define N_NODES   1024
#define N_GRAPHS  64

typedef __hip_bfloat16 bf16;
typedef __attribute__((ext_vector_type(8)))  short  short8;
typedef __attribute__((ext_vector_type(16))) float  f32x16;

__device__ __forceinline__ float bf2f(unsigned short s) {
    union { unsigned u; float f; } x; x.u = ((unsigned)s) << 16; return x.f;
}
__device__ __forceinline__ unsigned short f2bf(float f) {
    __hip_bfloat16 h = __float2bfloat16(f);
    return *reinterpret_cast<unsigned short*>(&h);
}
__device__ __forceinline__ uint4 pack8(const float* f) {
    uint4 r;
    r.x = f2bf(f[0]) | ((unsigned)f2bf(f[1]) << 16);
    r.y = f2bf(f[2]) | ((unsigned)f2bf(f[3]) << 16);
    r.z = f2bf(f[4]) | ((unsigned)f2bf(f[5]) << 16);
    r.w = f2bf(f[6]) | ((unsigned)f2bf(f[7]) << 16);
    return r;
}

// ---------------- deterministic adjacency build ----------------------------
__global__ __launch_bounds__(64) void k_build_adj(
    const int* __restrict__ edges, int per_g,
    int* __restrict__ cnt, int* __restrict__ lst)
{
    int n = blockIdx.x * 64 + threadIdx.x;
    if (n >= N_NODES) return;
    int g = n >> 4;
    const int* eg = edges + (size_t)g * per_g * 3;
    int c = 0;
    for (int k = 0; k < per_g; ++k) {
        int a = eg[k * 3 + 0];
        int s = eg[k * 3 + 1];
        int b = eg[k * 3 + 2];
        int other = (a == n) ? b : ((b == n) ? a : -1);
        if (other >= 0 && (other >> 4) == g && c < 16) {
            lst[n * 16 + c] = other | ((s < 0) ? (int)0x80000000 : 0);
            ++c;
        }
    }
    cnt[n] = c;
}

// ---------------- weight fragment pre-pack ---------------------------------
// wf[((kk*CIG + cg)*MT + m)*64 + lane][8]: co = m*32+(lane&31),
// ci = cg*16 + (lane>>5)*8 + j. Zero-padded beyond Cout/Cin.
__global__ __launch_bounds__(64) void k_prep_w(
    const float* __restrict__ w, unsigned short* __restrict__ wf,
    int Cin, int Cout)
{
    int kk = blockIdx.x, cg = blockIdx.y, m = blockIdx.z;
    int CIG = gridDim.y, MT = gridDim.z;
    int lane = threadIdx.x;
    int co = m * 32 + (lane & 31), kg = lane >> 5;
    float v[8];
    #pragma unroll
    for (int j = 0; j < 8; ++j) {
        int ci = cg * 16 + kg * 8 + j;
        v[j] = (co < Cout && ci < Cin) ? w[((size_t)co * Cin + ci) * 9 + kk] : 0.f;
    }
    *(uint4*)(wf + ((size_t)((kk * CIG + cg) * MT + m) * 64 + lane) * 8) = pack8(v);
}

// ---------------- embed -> grouped-HWC [nc][2][1024][8], ch9..15 zero ------
__global__ __launch_bounds__(256) void k_embed(
    const float* __restrict__ x, const float* __restrict__ t,
    const float* __restrict__ wt, const float* __restrict__ bt,
    bf16* __restrict__ out, int node_base)
{
    int nl = blockIdx.x, n = node_base + nl, tid = threadIdx.x;
    __shared__ float tl[10];
    if (tid < 10) tl[tid] = t[n * 10 + tid];
    __syncthreads();
    uint4* o4 = (uint4*)out;
    for (int p = 0; p < 4; ++p) {
        int px = tid + p * 256;
        float ch[16];
        ch[0] = x[(size_t)n * 1024 + px];
        #pragma unroll
        for (int c = 1; c <= 8; ++c) {
            int o = (c - 1) * 1024 + px;
            float a = bt[o];
            const float* wr = wt + (size_t)o * 10;
            #pragma unroll
            for (int k = 0; k < 10; ++k) a += wr[k] * tl[k];
            ch[c] = a;
        }
        #pragma unroll
        for (int c = 9; c < 16; ++c) ch[c] = 0.f;
        o4[(size_t)(nl * 2 + 0) * 1024 + px] = pack8(ch);
        o4[(size_t)(nl * 2 + 1) * 1024 + px] = pack8(ch + 8);
    }
}

// ---------------- MFMA conv 3x3 pad1 stride1 (per image) -------------------
template<int NPIX, int CIG16, int COUT, int RELU>
__global__ __launch_bounds__(256) void k_conv_mfma(
    const bf16* __restrict__ in, const unsigned short* __restrict__ wf,
    const float* __restrict__ bias, bf16* __restrict__ out)
{
    constexpr int W   = (NPIX == 1024) ? 32 : 16;
    constexpr int TPW = NPIX / 128;
    __shared__ __align__(16) short sbuf[2 * NPIX * 8 + 8];
    __shared__ float sbias[32];

    const int n   = blockIdx.x;
    const int tid = threadIdx.x;
    const int wid = tid >> 6, lane = tid & 63;
    const int pxl = lane & 31, kg = lane >> 5;

    if (tid < 8)  sbuf[2 * NPIX * 8 + tid] = 0;
    if (tid < 32) sbias[tid] = (tid < COUT) ? bias[tid] : 0.f;

    f32x16 acc[TPW];
    #pragma unroll
    for (int tt = 0; tt < TPW; ++tt)
        #pragma unroll
        for (int e = 0; e < 16; ++e) acc[tt][e] = 0.f;

    for (int ph = 0; ph < CIG16; ++ph) {
        __syncthreads();
        const uint4* src = (const uint4*)in + ((size_t)n * CIG16 + ph) * 2 * NPIX;
        uint4* dst = (uint4*)sbuf;
        for (int i = tid; i < 2 * NPIX; i += 256) dst[i] = src[i];
        __syncthreads();

        short8 wfr[9];
        #pragma unroll
        for (int kk = 0; kk < 9; ++kk)
            wfr[kk] = *(const short8*)(wf + ((size_t)(kk * CIG16 + ph) * 64 + lane) * 8);

        #pragma unroll
        for (int tt = 0; tt < TPW; ++tt) {
            int tile = wid * TPW + tt;
            int oy = (W == 32) ? tile : (tile * 2 + (pxl >> 4));
            int ox = (W == 32) ? pxl  : (pxl & 15);
            #pragma unroll
            for (int kk = 0; kk < 9; ++kk) {
                const int dy = kk / 3 - 1, dx = kk % 3 - 1;
                int iy = oy + dy, ix = ox + dx;
                bool ok = ((unsigned)iy < (unsigned)W) && ((unsigned)ix < (unsigned)W);
                int chunk = ok ? (kg * NPIX + iy * W + ix) : (2 * NPIX);
                const short8* bp = (const short8*)(sbuf + chunk * 8);
                acc[tt] = __builtin_amdgcn_mfma_f32_32x32x16_bf16(wfr[kk], *bp, acc[tt], 0, 0, 0);
            }
        }
    }

    unsigned short* outp = (unsigned short*)out;
    #pragma unroll
    for (int tt = 0; tt < TPW; ++tt) {
        int tile = wid * TPW + tt;
        int oy = (W == 32) ? tile : (tile * 2 + (pxl >> 4));
        int ox = (W == 32) ? pxl  : (pxl & 15);
        int opx = oy * W + ox;
        #pragma unroll
        for (int q = 0; q < COUT / 8; ++q) {
            unsigned short u[4];
            #pragma unroll
            for (int j = 0; j < 4; ++j) {
                int co = q * 8 + kg * 4 + j;
                float v = acc[tt][4 * q + j] + sbias[co];
                if (RELU) v = (v >= 0.f) ? v : 0.1f * v;
                u[j] = f2bf(v);
            }
            uint2 pk;
            pk.x = u[0] | ((unsigned)u[1] << 16);
            pk.y = u[2] | ((unsigned)u[3] << 16);
            *(uint2*)(outp + ((size_t)(n * (COUT / 8) + q) * NPIX + opx) * 8 + kg * 4) = pk;
        }
    }
}

// ---------------- MFMA stride-2 conv, images batched into N ----------------
// All tail convs have lrelu. FUSE_POOL: lrelu -> dot(pw) -> atomicAdd out[g].
template<int HIN, int CIG, int COUT, int IPB, int FUSE_POOL>
__global__ __launch_bounds__(256) void k_tail(
    const bf16* __restrict__ in, const unsigned short* __restrict__ wf,
    const float* __restrict__ bias, bf16* __restrict__ out,
    const int* __restrict__ nd, const float* __restrict__ pw,
    float* __restrict__ pool_out, int nc, int node_base)
{
    constexpr int HOUT = HIN / 2, NPO = HOUT * HOUT, NPI = HIN * HIN;
    constexpr int MT  = (COUT + 31) / 32;
    constexpr int NT  = (IPB * NPO) / 32;
    constexpr int TOT = MT * NT;
    constexpr int TPW = TOT / 4;
    static_assert(TOT % 4 == 0, "tile count must divide over 4 waves");
    constexpr int CHUNKS = IPB * 2 * CIG * NPI;
    __shared__ __align__(16) short sbuf[CHUNKS * 8 + 8];

    const int tid = threadIdx.x, wid = tid >> 6, lane = tid & 63;
    const int col = lane & 31, kg = lane >> 5;
    const int img0 = blockIdx.x * IPB;

    {
        const uint4* src = (const uint4*)in + (size_t)img0 * (2 * CIG * NPI);
        uint4* dst = (uint4*)sbuf;
        int nav = nc - img0; if (nav > IPB) nav = IPB;
        int nch = nav * 2 * CIG * NPI;
        uint4 z = {0, 0, 0, 0};
        for (int i = tid; i < CHUNKS; i += 256) dst[i] = (i < nch) ? src[i] : z;
        if (tid < 8) sbuf[CHUNKS * 8 + tid] = 0;
    }
    __syncthreads();

    int imgb[TPW], poff[TPW][9];
    #pragma unroll
    for (int t = 0; t < TPW; ++t) {
        int tl = wid + 4 * t;
        int n  = tl % NT;
        int idx = n * 32 + col;
        int img = idx / NPO, px = idx % NPO;
        imgb[t] = img * (2 * CIG * NPI);
        int oy = px / HOUT, ox = px % HOUT;
        #pragma unroll
        for (int kk = 0; kk < 9; ++kk) {
            int iy = 2 * oy + kk / 3 - 1, ix = 2 * ox + kk % 3 - 1;
            bool ok = ((unsigned)iy < (unsigned)HIN) && ((unsigned)ix < (unsigned)HIN);
            poff[t][kk] = ok ? (iy * HIN + ix) : -1;
        }
    }

    f32x16 acc[TPW];
    #pragma unroll
    for (int t = 0; t < TPW; ++t)
        #pragma unroll
        for (int e = 0; e < 16; ++e) acc[t][e] = 0.f;

    for (int cig = 0; cig < CIG; ++cig) {
        #pragma unroll
        for (int t = 0; t < TPW; ++t) {
            int m = (wid + 4 * t) / NT;
            #pragma unroll
            for (int kk = 0; kk < 9; ++kk) {
                short8 wfr = *(const short8*)(wf +
                    ((size_t)((kk * CIG + cig) * MT + m) * 64 + lane) * 8);
                int chunk = (poff[t][kk] >= 0)
                          ? imgb[t] + (cig * 2 + kg) * NPI + poff[t][kk]
                          : CHUNKS;
                acc[t] = __builtin_amdgcn_mfma_f32_32x32x16_bf16(
                            wfr, *(const short8*)(sbuf + chunk * 8), acc[t], 0, 0, 0);
            }
        }
    }

    #pragma unroll
    for (int t = 0; t < TPW; ++t) {
        int tl = wid + 4 * t;
        int m = tl / NT, n = tl % NT;
        int idx = n * 32 + col;
        int img = idx / NPO, px = idx % NPO;
        bool live = (img0 + img) < nc;
        if (FUSE_POOL) {
            float part = 0.f;
            #pragma unroll
            for (int r = 0; r < 16; ++r) {
                int co = m * 32 + (r & 3) + 8 * (r >> 2) + 4 * kg;
                float v = acc[t][r] + bias[co];
                v = (v >= 0.f) ? v : 0.1f * v;
                part += v * pw[co];
            }
            part += __shfl_xor(part, 32, 64);
            if (kg == 0 && live) {
                int g = nd[node_base + img0 + img];
                if (g < 0) g = 0; if (g >= N_GRAPHS) g = N_GRAPHS - 1;
                atomicAdd(&pool_out[g], part);
            }
        } else if (live) {
            unsigned short* outp = (unsigned short*)out;
            #pragma unroll
            for (int q = 0; q < 4; ++q) {
                if (m * 32 + q * 8 < COUT) {
                    unsigned short u[4];
                    #pragma unroll
                    for (int j = 0; j < 4; ++j) {
                        int co = m * 32 + q * 8 + kg * 4 + j;
                        float v = acc[t][4 * q + j] + bias[co];
                        v = (v >= 0.f) ? v : 0.1f * v;
                        u[j] = f2bf(v);
                    }
                    uint2 pk;
                    pk.x = u[0] | ((unsigned)u[1] << 16);
                    pk.y = u[2] | ((unsigned)u[3] << 16);
                    *(uint2*)(outp + (((size_t)(img0 + img) * (COUT / 8)
                              + (m * 4 + q)) * NPO + px) * 8 + kg * 4) = pk;
                }
            }
        }
    }
}

// ---------------- MPN gather: [self | pos-sum | neg-sum], grouped-HWC ------
template<int NPIX>
__global__ __launch_bounds__(256) void k_gather(
    const bf16* __restrict__ in, const int* __restrict__ cnt,
    const int* __restrict__ lst, bf16* __restrict__ out, int node_base)
{
    constexpr int CPN = 2 * NPIX;
    const int gl = blockIdx.x, split = blockIdx.y, tid = threadIdx.x;
    const int gn0 = node_base + gl * 16;
    const int nl0 = gl * 16;
    __shared__ int s_adj[16][16];
    __shared__ int s_cnt[16];
    if (tid < 16) s_cnt[tid] = cnt[gn0 + tid];
    s_adj[tid >> 4][tid & 15] = lst[(size_t)(gn0 + (tid >> 4)) * 16 + (tid & 15)];
    __syncthreads();

    int pos = split * 256 + tid;
    const uint4* in4 = (const uint4*)in;
    uint4* out4 = (uint4*)out;

    for (int l = 0; l < 16; ++l) {
        int nl = nl0 + l;
        uint4 self = in4[(size_t)nl * CPN + pos];
        float P[8], Nn[8];
        #pragma unroll
        for (int j = 0; j < 8; ++j) { P[j] = 0.f; Nn[j] = 0.f; }
        int c = s_cnt[l];
        for (int k = 0; k < c; ++k) {
            int e = s_adj[l][k];
            int sl = (e & 0x7FFFFFFF) - node_base;
            union { uint4 v; unsigned short s[8]; } u;
            u.v = in4[(size_t)sl * CPN + pos];
            if (e < 0) {
                #pragma unroll
                for (int j = 0; j < 8; ++j) Nn[j] += bf2f(u.s[j]);
            } else {
                #pragma unroll
                for (int j = 0; j < 8; ++j) P[j] += bf2f(u.s[j]);
            }
        }
        size_t ob = (size_t)nl * 3 * CPN + pos;
        out4[ob]           = self;
        out4[ob + CPN]     = pack8(P);
        out4[ob + 2 * CPN] = pack8(Nn);
    }
}

// ---------------- head init -------------------------------------------------
__global__ void k_init_out(float* out, const float* __restrict__ pb)
{
    int i = threadIdx.x;
    if (i < N_GRAPHS) out[i] = pb[0];
}

// ---------------------------------------------------------------------------
extern "C" void kernel_launch(void* const* d_in, const int* in_sizes, int n_in,
                              void* d_out, int out_size, void* d_ws, size_t ws_size,
                              hipStream_t stream)
{
    const float* x     = (const float*)d_in[0];
    const float* t     = (const float*)d_in[1];
    const int*   edges = (const int*)d_in[2];
    const int*   nd    = (const int*)d_in[3];
    const float* w_t   = (const float*)d_in[4];
    const float* b_t   = (const float*)d_in[5];
    const float* c1w   = (const float*)d_in[6];
    const float* c1b   = (const float*)d_in[7];
    const float* c2w   = (const float*)d_in[8];
    const float* c2b   = (const float*)d_in[9];
    const float* c3w   = (const float*)d_in[10];
    const float* c3b   = (const float*)d_in[11];
    const float* m1c1w = (const float*)d_in[12];
    const float* m1c1b = (const float*)d_in[13];
    const float* m1c2w = (const float*)d_in[14];
    const float* m1c2b = (const float*)d_in[15];
    const float* m1c3w = (const float*)d_in[16];
    const float* m1c3b = (const float*)d_in[17];
    const float* ds1w  = (const float*)d_in[18];
    const float* ds1b  = (const float*)d_in[19];
    const float* m2c1w = (const float*)d_in[20];
    const float* m2c1b = (const float*)d_in[21];
    const float* m2c2w = (const float*)d_in[22];
    const float* m2c2b = (const float*)d_in[23];
    const float* m2c3w = (const float*)d_in[24];
    const float* m2c3b = (const float*)d_in[25];
    const float* ds2w  = (const float*)d_in[26];
    const float* ds2b  = (const float*)d_in[27];
    const float* d1w   = (const float*)d_in[28];
    const float* d1b   = (const float*)d_in[29];
    const float* d2w   = (const float*)d_in[30];
    const float* d2b   = (const float*)d_in[31];
    const float* d3w   = (const float*)d_in[32];
    const float* d3b   = (const float*)d_in[33];
    const float* pw    = (const float*)d_in[34];
    const float* pb    = (const float*)d_in[35];
    float* out = (float*)d_out;

    uint8_t* ws = (uint8_t*)d_ws;
    int* adj_cnt = (int*)ws;                         // [0, 4K)
    int* adj_lst = (int*)(ws + 4096);                // [4K, 68K)
    // main conv weight fragments: 9 slots x 32 KB at [128K, 416K)
    #define WF(i)  ((unsigned short*)(ws + (128u << 10) + (size_t)(i) * 32768))
    // tail weight fragments
    unsigned short* wt_ds1 = (unsigned short*)(ws + (416u  << 10)); //   9 KB
    unsigned short* wt_ds2 = (unsigned short*)(ws + (428u  << 10)); //   9 KB
    unsigned short* wt_d1  = (unsigned short*)(ws + (440u  << 10)); //  72 KB
    unsigned short* wt_d2  = (unsigned short*)(ws + (512u  << 10)); // 576 KB
    unsigned short* wt_d3  = (unsigned short*)(ws + (1088u << 10)); // 288 KB

    // ---- adaptive chunking: liveness-packed pool, 160 KiB per node --------
    const size_t RESV = 2ull << 20;
    size_t avail = (ws_size > RESV) ? ws_size - RESV : 0;
    int ncap = (int)(avail / (160 * 1024));
    ncap = (ncap / 16) * 16;
    if (ncap < 16) ncap = 16;
    if (ncap > N_NODES) ncap = N_NODES;
    uint8_t* R = ws + RESV;
    #define NB(off_kb) (R + (size_t)(off_kb) * 1024 * ncap)

    bf16*  h0    = (bf16*)NB(0);      // [0,32)
    bf16*  c1o   = (bf16*)NB(32);     // [32,64)
    bf16*  c2o   = (bf16*)NB(64);     // [64,96)
    bf16*  c3o   = (bf16*)NB(128);    // [128,160)
    bf16*  g1    = (bf16*)NB(0);      // [0,96)
    bf16*  m1c1o = (bf16*)NB(96);     // [96,160)
    bf16*  m1c2o = (bf16*)NB(0);      // [0,64)
    bf16*  m1c3o = (bf16*)NB(64);     // [64,96)
    bf16*  ds1o  = (bf16*)NB(0);      // [0,8)
    bf16*  g2    = (bf16*)NB(8);      // [8,32)
    bf16*  m2c1o = (bf16*)NB(32);     // [32,48)
    bf16*  m2c2o = (bf16*)NB(0);      // [0,16)
    bf16*  m2c3o = (bf16*)NB(16);     // [16,24)
    bf16*  ds2o  = (bf16*)NB(24);     // [24,26)  grouped (16ch, 8x8)
    bf16*  d1o   = (bf16*)NB(0);      // [0,8)    grouped (256ch, 4x4)
    bf16*  d2o   = (bf16*)NB(8);      // [8,9)    grouped (128ch, 2x2)

    int nE    = in_sizes[2] / 3;
    int per_g = nE / N_GRAPHS;

    k_build_adj<<<(N_NODES + 63) / 64, 64, 0, stream>>>(edges, per_g, adj_cnt, adj_lst);
    k_init_out<<<1, 64, 0, stream>>>(out, pb);

    // main convs (MT=1)
    k_prep_w<<<dim3(9, 1, 1), 64, 0, stream>>>(c1w,   WF(0), 9,  16);
    k_prep_w<<<dim3(9, 1, 1), 64, 0, stream>>>(c2w,   WF(1), 16, 16);
    k_prep_w<<<dim3(9, 1, 1), 64, 0, stream>>>(c3w,   WF(2), 16, 16);
    k_prep_w<<<dim3(9, 3, 1), 64, 0, stream>>>(m1c1w, WF(3), 48, 32);
    k_prep_w<<<dim3(9, 2, 1), 64, 0, stream>>>(m1c2w, WF(4), 32, 32);
    k_prep_w<<<dim3(9, 2, 1), 64, 0, stream>>>(m1c3w, WF(5), 32, 16);
    k_prep_w<<<dim3(9, 3, 1), 64, 0, stream>>>(m2c1w, WF(6), 48, 32);
    k_prep_w<<<dim3(9, 2, 1), 64, 0, stream>>>(m2c2w, WF(7), 32, 32);
    k_prep_w<<<dim3(9, 2, 1), 64, 0, stream>>>(m2c3w, WF(8), 32, 16);
    // tail convs
    k_prep_w<<<dim3(9, 1, 1),  64, 0, stream>>>(ds1w, wt_ds1, 16,  16);
    k_prep_w<<<dim3(9, 1, 1),  64, 0, stream>>>(ds2w, wt_ds2, 16,  16);
    k_prep_w<<<dim3(9, 1, 8),  64, 0, stream>>>(d1w,  wt_d1,  16,  256);
    k_prep_w<<<dim3(9, 16, 4), 64, 0, stream>>>(d2w,  wt_d2,  256, 128);
    k_prep_w<<<dim3(9, 8, 4),  64, 0, stream>>>(d3w,  wt_d3,  128, 128);

    for (int nb = 0; nb < N_NODES; nb += ncap) {
        int nc = (N_NODES - nb < ncap) ? (N_NODES - nb) : ncap;
        int ng = nc / 16;

        k_embed<<<nc, 256, 0, stream>>>(x, t, w_t, b_t, h0, nb);

        k_conv_mfma<1024, 1, 16, 1><<<nc, 256, 0, stream>>>(h0,  WF(0), c1b, c1o);
        k_conv_mfma<1024, 1, 16, 1><<<nc, 256, 0, stream>>>(c1o, WF(1), c2b, c2o);
        k_conv_mfma<1024, 1, 16, 1><<<nc, 256, 0, stream>>>(c2o, WF(2), c3b, c3o);

        k_gather<1024><<<dim3(ng, 8), 256, 0, stream>>>(c3o, adj_cnt, adj_lst, g1, nb);
        k_conv_mfma<1024, 3, 32, 0><<<nc, 256, 0, stream>>>(g1,    WF(3), m1c1b, m1c1o);
        k_conv_mfma<1024, 2, 32, 0><<<nc, 256, 0, stream>>>(m1c1o, WF(4), m1c2b, m1c2o);
        k_conv_mfma<1024, 2, 16, 0><<<nc, 256, 0, stream>>>(m1c2o, WF(5), m1c3b, m1c3o);

        // ds1: 32->16, 16ch
        k_tail<32, 1, 16, 1, 0><<<nc, 256, 0, stream>>>(
            m1c3o, wt_ds1, ds1b, ds1o, nullptr, nullptr, nullptr, nc, nb);

        k_gather<256><<<dim3(ng, 2), 256, 0, stream>>>(ds1o, adj_cnt, adj_lst, g2, nb);
        k_conv_mfma<256, 3, 32, 0><<<nc, 256, 0, stream>>>(g2,    WF(6), m2c1b, m2c1o);
        k_conv_mfma<256, 2, 32, 0><<<nc, 256, 0, stream>>>(m2c1o, WF(7), m2c2b, m2c2o);
        k_conv_mfma<256, 2, 16, 0><<<nc, 256, 0, stream>>>(m2c2o, WF(8), m2c3b, m2c3o);

        // ds2: 16->8, 16ch
        k_tail<16, 1, 16, 2, 0><<<(nc + 1) / 2, 256, 0, stream>>>(
            m2c3o, wt_ds2, ds2b, ds2o, nullptr, nullptr, nullptr, nc, nb);
        // d1: 8->4, 16->256
        k_tail<8, 1, 256, 4, 0><<<(nc + 3) / 4, 256, 0, stream>>>(
            ds2o, wt_d1, d1b, d1o, nullptr, nullptr, nullptr, nc, nb);
        // d2: 4->2, 256->128
        k_tail<4, 16, 128, 8, 0><<<(nc + 7) / 8, 256, 0, stream>>>(
            d1o, wt_d2, d2b, d2o, nullptr, nullptr, nullptr, nc, nb);
        // d3: 2->1, 128->128, fused pool
        k_tail<2, 8, 128, 32, 1><<<(nc + 31) / 32, 256, 0, stream>>>(
            d2o, wt_d3, d3b, nullptr, nd, pw, out, nc, nb);
    }
    #undef NB
    #undef WF
}

// Round 7
// 445.570 us; speedup vs baseline: 5.4962x; 1.2843x over previous
//
#include <hip/hip_runtime.h>
#include <hip/hip_bf16.h>

// ---------------------------------------------------------------------------
// Discriminator (HouseGAN-style), full-MFMA version.
// Activations: grouped-HWC bf16  [n][ci/8][px][8ci]  (16B chunks per px).
// r7: read-once LDS gather (pos/neg only) + SELFSPLIT conv (self phase reads
// the conv input buffer directly; gather buffer holds only pos|neg sums).
// MFMA fragment layouts (verified r5): A m=lane&31,k=(lane>>5)*8+j;
// B col=lane&31; C col=lane&31,row=(reg&3)+8*(reg>>2)+4*(lane>>5).
// ---------------------------------------------------------------------------

#define N_NODES   1024
#define N_GRAPHS  64

typedef __hip_bfloat16 bf16;
typedef __attribute__((ext_vector_type(8)))  short  short8;
typedef __attribute__((ext_vector_type(16))) float  f32x16;

__device__ __forceinline__ float bf2f(unsigned short s) {
    union { unsigned u; float f; } x; x.u = ((unsigned)s) << 16; return x.f;
}
__device__ __forceinline__ unsigned short f2bf(float f) {
    __hip_bfloat16 h = __float2bfloat16(f);
    return *reinterpret_cast<unsigned short*>(&h);
}
__device__ __forceinline__ uint4 pack8(const float* f) {
    uint4 r;
    r.x = f2bf(f[0]) | ((unsigned)f2bf(f[1]) << 16);
    r.y = f2bf(f[2]) | ((unsigned)f2bf(f[3]) << 16);
    r.z = f2bf(f[4]) | ((unsigned)f2bf(f[5]) << 16);
    r.w = f2bf(f[6]) | ((unsigned)f2bf(f[7]) << 16);
    return r;
}

// ---------------- deterministic adjacency build ----------------------------
__global__ __launch_bounds__(64) void k_build_adj(
    const int* __restrict__ edges, int per_g,
    int* __restrict__ cnt, int* __restrict__ lst)
{
    int n = blockIdx.x * 64 + threadIdx.x;
    if (n >= N_NODES) return;
    int g = n >> 4;
    const int* eg = edges + (size_t)g * per_g * 3;
    int c = 0;
    for (int k = 0; k < per_g; ++k) {
        int a = eg[k * 3 + 0];
        int s = eg[k * 3 + 1];
        int b = eg[k * 3 + 2];
        int other = (a == n) ? b : ((b == n) ? a : -1);
        if (other >= 0 && (other >> 4) == g && c < 16) {
            lst[n * 16 + c] = other | ((s < 0) ? (int)0x80000000 : 0);
            ++c;
        }
    }
    cnt[n] = c;
}

// ---------------- weight fragment pre-pack ---------------------------------
__global__ __launch_bounds__(64) void k_prep_w(
    const float* __restrict__ w, unsigned short* __restrict__ wf,
    int Cin, int Cout)
{
    int kk = blockIdx.x, cg = blockIdx.y, m = blockIdx.z;
    int CIG = gridDim.y, MT = gridDim.z;
    int lane = threadIdx.x;
    int co = m * 32 + (lane & 31), kg = lane >> 5;
    float v[8];
    #pragma unroll
    for (int j = 0; j < 8; ++j) {
        int ci = cg * 16 + kg * 8 + j;
        v[j] = (co < Cout && ci < Cin) ? w[((size_t)co * Cin + ci) * 9 + kk] : 0.f;
    }
    *(uint4*)(wf + ((size_t)((kk * CIG + cg) * MT + m) * 64 + lane) * 8) = pack8(v);
}

// ---------------- embed -> grouped-HWC [nc][2][1024][8], ch9..15 zero ------
__global__ __launch_bounds__(256) void k_embed(
    const float* __restrict__ x, const float* __restrict__ t,
    const float* __restrict__ wt, const float* __restrict__ bt,
    bf16* __restrict__ out, int node_base)
{
    int nl = blockIdx.x, n = node_base + nl, tid = threadIdx.x;
    __shared__ float tl[10];
    if (tid < 10) tl[tid] = t[n * 10 + tid];
    __syncthreads();
    uint4* o4 = (uint4*)out;
    for (int p = 0; p < 4; ++p) {
        int px = tid + p * 256;
        float ch[16];
        ch[0] = x[(size_t)n * 1024 + px];
        #pragma unroll
        for (int c = 1; c <= 8; ++c) {
            int o = (c - 1) * 1024 + px;
            float a = bt[o];
            const float* wr = wt + (size_t)o * 10;
            #pragma unroll
            for (int k = 0; k < 10; ++k) a += wr[k] * tl[k];
            ch[c] = a;
        }
        #pragma unroll
        for (int c = 9; c < 16; ++c) ch[c] = 0.f;
        o4[(size_t)(nl * 2 + 0) * 1024 + px] = pack8(ch);
        o4[(size_t)(nl * 2 + 1) * 1024 + px] = pack8(ch + 8);
    }
}

// ---------------- read-once LDS gather: pos/neg sums only ------------------
// block = (graph, 128-chunk window). Stage 16 node windows in LDS once,
// accumulate per-dest via adjacency bitmasks (SGPR), write [node][2][CPN].
template<int NPIX>
__global__ __launch_bounds__(256) void k_gather2(
    const bf16* __restrict__ in, const int* __restrict__ cnt,
    const int* __restrict__ lst, bf16* __restrict__ out, int node_base)
{
    constexpr int CPN = 2 * NPIX;
    __shared__ __align__(16) uint4 s_in[16 * 128];
    __shared__ int s_pos[16], s_neg[16];

    const int gl = blockIdx.x, sp = blockIdx.y, tid = threadIdx.x;
    const int gn0 = node_base + gl * 16, nl0 = gl * 16;

    if (tid < 16) {
        int c = cnt[gn0 + tid]; if (c > 16) c = 16;
        int pm = 0, nm = 0;
        for (int k = 0; k < c; ++k) {
            int e = lst[(size_t)(gn0 + tid) * 16 + k];
            int sl = (e & 0x7FFFFFFF) - gn0;
            if ((unsigned)sl < 16u) { if (e < 0) nm |= 1 << sl; else pm |= 1 << sl; }
        }
        s_pos[tid] = pm; s_neg[tid] = nm;
    }
    const uint4* in4 = (const uint4*)in;
    for (int i = tid; i < 2048; i += 256) {
        int srcn = i >> 7, chk = i & 127;
        s_in[i] = in4[(size_t)(nl0 + srcn) * CPN + sp * 128 + chk];
    }
    __syncthreads();

    const int dh = tid >> 7, ch = tid & 127;
    int pm[8], nm[8];
    #pragma unroll
    for (int dl = 0; dl < 8; ++dl) {
        pm[dl] = __builtin_amdgcn_readfirstlane(s_pos[dh * 8 + dl]);
        nm[dl] = __builtin_amdgcn_readfirstlane(s_neg[dh * 8 + dl]);
    }

    float aP[8][8], aN[8][8];
    #pragma unroll
    for (int dl = 0; dl < 8; ++dl)
        #pragma unroll
        for (int j = 0; j < 8; ++j) { aP[dl][j] = 0.f; aN[dl][j] = 0.f; }

    for (int s = 0; s < 16; ++s) {
        union { uint4 v; unsigned short u[8]; } q;
        q.v = s_in[s * 128 + ch];
        float f[8];
        #pragma unroll
        for (int j = 0; j < 8; ++j) f[j] = bf2f(q.u[j]);
        #pragma unroll
        for (int dl = 0; dl < 8; ++dl) {
            if ((pm[dl] >> s) & 1) {
                #pragma unroll
                for (int j = 0; j < 8; ++j) aP[dl][j] += f[j];
            }
            if ((nm[dl] >> s) & 1) {
                #pragma unroll
                for (int j = 0; j < 8; ++j) aN[dl][j] += f[j];
            }
        }
    }

    uint4* out4 = (uint4*)out;
    #pragma unroll
    for (int dl = 0; dl < 8; ++dl) {
        int d = nl0 + dh * 8 + dl;
        out4[((size_t)d * 2 + 0) * CPN + sp * 128 + ch] = pack8(aP[dl]);
        out4[((size_t)d * 2 + 1) * CPN + sp * 128 + ch] = pack8(aN[dl]);
    }
}

// ---------------- MFMA conv 3x3 pad1 stride1 (per image) -------------------
// SELFSPLIT: phase 0 stages from `in` ([n][2*NPIX] chunks), phases 1-2 from
// `in2` ([n][2][2*NPIX] chunks = pos|neg gather sums).
template<int NPIX, int CIG16, int COUT, int RELU, bool SELFSPLIT>
__global__ __launch_bounds__(256) void k_conv_mfma(
    const bf16* __restrict__ in, const bf16* __restrict__ in2,
    const unsigned short* __restrict__ wf,
    const float* __restrict__ bias, bf16* __restrict__ out)
{
    constexpr int W   = (NPIX == 1024) ? 32 : 16;
    constexpr int TPW = NPIX / 128;
    __shared__ __align__(16) short sbuf[2 * NPIX * 8 + 8];
    __shared__ float sbias[32];

    const int n   = blockIdx.x;
    const int tid = threadIdx.x;
    const int wid = tid >> 6, lane = tid & 63;
    const int pxl = lane & 31, kg = lane >> 5;

    if (tid < 8)  sbuf[2 * NPIX * 8 + tid] = 0;
    if (tid < 32) sbias[tid] = (tid < COUT) ? bias[tid] : 0.f;

    f32x16 acc[TPW];
    #pragma unroll
    for (int tt = 0; tt < TPW; ++tt)
        #pragma unroll
        for (int e = 0; e < 16; ++e) acc[tt][e] = 0.f;

    for (int ph = 0; ph < CIG16; ++ph) {
        __syncthreads();
        const uint4* src;
        if constexpr (SELFSPLIT) {
            src = (ph == 0)
                ? (const uint4*)in  + (size_t)n * (2 * NPIX)
                : (const uint4*)in2 + ((size_t)n * 2 + (ph - 1)) * (2 * NPIX);
        } else {
            src = (const uint4*)in + ((size_t)n * CIG16 + ph) * (2 * NPIX);
        }
        uint4* dst = (uint4*)sbuf;
        for (int i = tid; i < 2 * NPIX; i += 256) dst[i] = src[i];
        __syncthreads();

        short8 wfr[9];
        #pragma unroll
        for (int kk = 0; kk < 9; ++kk)
            wfr[kk] = *(const short8*)(wf + ((size_t)(kk * CIG16 + ph) * 64 + lane) * 8);

        #pragma unroll
        for (int tt = 0; tt < TPW; ++tt) {
            int tile = wid * TPW + tt;
            int oy = (W == 32) ? tile : (tile * 2 + (pxl >> 4));
            int ox = (W == 32) ? pxl  : (pxl & 15);
            #pragma unroll
            for (int kk = 0; kk < 9; ++kk) {
                const int dy = kk / 3 - 1, dx = kk % 3 - 1;
                int iy = oy + dy, ix = ox + dx;
                bool ok = ((unsigned)iy < (unsigned)W) && ((unsigned)ix < (unsigned)W);
                int chunk = ok ? (kg * NPIX + iy * W + ix) : (2 * NPIX);
                const short8* bp = (const short8*)(sbuf + chunk * 8);
                acc[tt] = __builtin_amdgcn_mfma_f32_32x32x16_bf16(wfr[kk], *bp, acc[tt], 0, 0, 0);
            }
        }
    }

    unsigned short* outp = (unsigned short*)out;
    #pragma unroll
    for (int tt = 0; tt < TPW; ++tt) {
        int tile = wid * TPW + tt;
        int oy = (W == 32) ? tile : (tile * 2 + (pxl >> 4));
        int ox = (W == 32) ? pxl  : (pxl & 15);
        int opx = oy * W + ox;
        #pragma unroll
        for (int q = 0; q < COUT / 8; ++q) {
            unsigned short u[4];
            #pragma unroll
            for (int j = 0; j < 4; ++j) {
                int co = q * 8 + kg * 4 + j;
                float v = acc[tt][4 * q + j] + sbias[co];
                if (RELU) v = (v >= 0.f) ? v : 0.1f * v;
                u[j] = f2bf(v);
            }
            uint2 pk;
            pk.x = u[0] | ((unsigned)u[1] << 16);
            pk.y = u[2] | ((unsigned)u[3] << 16);
            *(uint2*)(outp + ((size_t)(n * (COUT / 8) + q) * NPIX + opx) * 8 + kg * 4) = pk;
        }
    }
}

// ---------------- MFMA stride-2 conv, images batched into N ----------------
template<int HIN, int CIG, int COUT, int IPB, int FUSE_POOL>
__global__ __launch_bounds__(256) void k_tail(
    const bf16* __restrict__ in, const unsigned short* __restrict__ wf,
    const float* __restrict__ bias, bf16* __restrict__ out,
    const int* __restrict__ nd, const float* __restrict__ pw,
    float* __restrict__ pool_out, int nc, int node_base)
{
    constexpr int HOUT = HIN / 2, NPO = HOUT * HOUT, NPI = HIN * HIN;
    constexpr int MT  = (COUT + 31) / 32;
    constexpr int NT  = (IPB * NPO) / 32;
    constexpr int TOT = MT * NT;
    constexpr int TPW = TOT / 4;
    static_assert(TOT % 4 == 0, "tile count must divide over 4 waves");
    constexpr int CHUNKS = IPB * 2 * CIG * NPI;
    __shared__ __align__(16) short sbuf[CHUNKS * 8 + 8];

    const int tid = threadIdx.x, wid = tid >> 6, lane = tid & 63;
    const int col = lane & 31, kg = lane >> 5;
    const int img0 = blockIdx.x * IPB;

    {
        const uint4* src = (const uint4*)in + (size_t)img0 * (2 * CIG * NPI);
        uint4* dst = (uint4*)sbuf;
        int nav = nc - img0; if (nav > IPB) nav = IPB;
        int nch = nav * 2 * CIG * NPI;
        uint4 z = {0, 0, 0, 0};
        for (int i = tid; i < CHUNKS; i += 256) dst[i] = (i < nch) ? src[i] : z;
        if (tid < 8) sbuf[CHUNKS * 8 + tid] = 0;
    }
    __syncthreads();

    int imgb[TPW], poff[TPW][9];
    #pragma unroll
    for (int t = 0; t < TPW; ++t) {
        int tl = wid + 4 * t;
        int n  = tl % NT;
        int idx = n * 32 + col;
        int img = idx / NPO, px = idx % NPO;
        imgb[t] = img * (2 * CIG * NPI);
        int oy = px / HOUT, ox = px % HOUT;
        #pragma unroll
        for (int kk = 0; kk < 9; ++kk) {
            int iy = 2 * oy + kk / 3 - 1, ix = 2 * ox + kk % 3 - 1;
            bool ok = ((unsigned)iy < (unsigned)HIN) && ((unsigned)ix < (unsigned)HIN);
            poff[t][kk] = ok ? (iy * HIN + ix) : -1;
        }
    }

    f32x16 acc[TPW];
    #pragma unroll
    for (int t = 0; t < TPW; ++t)
        #pragma unroll
        for (int e = 0; e < 16; ++e) acc[t][e] = 0.f;

    for (int cig = 0; cig < CIG; ++cig) {
        #pragma unroll
        for (int t = 0; t < TPW; ++t) {
            int m = (wid + 4 * t) / NT;
            #pragma unroll
            for (int kk = 0; kk < 9; ++kk) {
                short8 wfr = *(const short8*)(wf +
                    ((size_t)((kk * CIG + cig) * MT + m) * 64 + lane) * 8);
                int chunk = (poff[t][kk] >= 0)
                          ? imgb[t] + (cig * 2 + kg) * NPI + poff[t][kk]
                          : CHUNKS;
                acc[t] = __builtin_amdgcn_mfma_f32_32x32x16_bf16(
                            wfr, *(const short8*)(sbuf + chunk * 8), acc[t], 0, 0, 0);
            }
        }
    }

    #pragma unroll
    for (int t = 0; t < TPW; ++t) {
        int tl = wid + 4 * t;
        int m = tl / NT, n = tl % NT;
        int idx = n * 32 + col;
        int img = idx / NPO, px = idx % NPO;
        bool live = (img0 + img) < nc;
        if (FUSE_POOL) {
            float part = 0.f;
            #pragma unroll
            for (int r = 0; r < 16; ++r) {
                int co = m * 32 + (r & 3) + 8 * (r >> 2) + 4 * kg;
                float v = acc[t][r] + bias[co];
                v = (v >= 0.f) ? v : 0.1f * v;
                part += v * pw[co];
            }
            part += __shfl_xor(part, 32, 64);
            if (kg == 0 && live) {
                int g = nd[node_base + img0 + img];
                if (g < 0) g = 0; if (g >= N_GRAPHS) g = N_GRAPHS - 1;
                atomicAdd(&pool_out[g], part);
            }
        } else if (live) {
            unsigned short* outp = (unsigned short*)out;
            #pragma unroll
            for (int q = 0; q < 4; ++q) {
                if (m * 32 + q * 8 < COUT) {
                    unsigned short u[4];
                    #pragma unroll
                    for (int j = 0; j < 4; ++j) {
                        int co = m * 32 + q * 8 + kg * 4 + j;
                        float v = acc[t][4 * q + j] + bias[co];
                        v = (v >= 0.f) ? v : 0.1f * v;
                        u[j] = f2bf(v);
                    }
                    uint2 pk;
                    pk.x = u[0] | ((unsigned)u[1] << 16);
                    pk.y = u[2] | ((unsigned)u[3] << 16);
                    *(uint2*)(outp + (((size_t)(img0 + img) * (COUT / 8)
                              + (m * 4 + q)) * NPO + px) * 8 + kg * 4) = pk;
                }
            }
        }
    }
}

// ---------------- head init -------------------------------------------------
__global__ void k_init_out(float* out, const float* __restrict__ pb)
{
    int i = threadIdx.x;
    if (i < N_GRAPHS) out[i] = pb[0];
}

// ---------------------------------------------------------------------------
extern "C" void kernel_launch(void* const* d_in, const int* in_sizes, int n_in,
                              void* d_out, int out_size, void* d_ws, size_t ws_size,
                              hipStream_t stream)
{
    const float* x     = (const float*)d_in[0];
    const float* t     = (const float*)d_in[1];
    const int*   edges = (const int*)d_in[2];
    const int*   nd    = (const int*)d_in[3];
    const float* w_t   = (const float*)d_in[4];
    const float* b_t   = (const float*)d_in[5];
    const float* c1w   = (const float*)d_in[6];
    const float* c1b   = (const float*)d_in[7];
    const float* c2w   = (const float*)d_in[8];
    const float* c2b   = (const float*)d_in[9];
    const float* c3w   = (const float*)d_in[10];
    const float* c3b   = (const float*)d_in[11];
    const float* m1c1w = (const float*)d_in[12];
    const float* m1c1b = (const float*)d_in[13];
    const float* m1c2w = (const float*)d_in[14];
    const float* m1c2b = (const float*)d_in[15];
    const float* m1c3w = (const float*)d_in[16];
    const float* m1c3b = (const float*)d_in[17];
    const float* ds1w  = (const float*)d_in[18];
    const float* ds1b  = (const float*)d_in[19];
    const float* m2c1w = (const float*)d_in[20];
    const float* m2c1b = (const float*)d_in[21];
    const float* m2c2w = (const float*)d_in[22];
    const float* m2c2b = (const float*)d_in[23];
    const float* m2c3w = (const float*)d_in[24];
    const float* m2c3b = (const float*)d_in[25];
    const float* ds2w  = (const float*)d_in[26];
    const float* ds2b  = (const float*)d_in[27];
    const float* d1w   = (const float*)d_in[28];
    const float* d1b   = (const float*)d_in[29];
    const float* d2w   = (const float*)d_in[30];
    const float* d2b   = (const float*)d_in[31];
    const float* d3w   = (const float*)d_in[32];
    const float* d3b   = (const float*)d_in[33];
    const float* pw    = (const float*)d_in[34];
    const float* pb    = (const float*)d_in[35];
    float* out = (float*)d_out;

    uint8_t* ws = (uint8_t*)d_ws;
    int* adj_cnt = (int*)ws;                         // [0, 4K)
    int* adj_lst = (int*)(ws + 4096);                // [4K, 68K)
    #define WF(i)  ((unsigned short*)(ws + (128u << 10) + (size_t)(i) * 32768))
    unsigned short* wt_ds1 = (unsigned short*)(ws + (416u  << 10));
    unsigned short* wt_ds2 = (unsigned short*)(ws + (428u  << 10));
    unsigned short* wt_d1  = (unsigned short*)(ws + (440u  << 10));
    unsigned short* wt_d2  = (unsigned short*)(ws + (512u  << 10));
    unsigned short* wt_d3  = (unsigned short*)(ws + (1088u << 10));

    // ---- adaptive chunking: liveness-packed pool, 192 KiB per node --------
    const size_t RESV = 2ull << 20;
    size_t avail = (ws_size > RESV) ? ws_size - RESV : 0;
    int ncap = (int)(avail / (192 * 1024));
    ncap = (ncap / 16) * 16;
    if (ncap < 16) ncap = 16;
    if (ncap > N_NODES) ncap = N_NODES;
    uint8_t* R = ws + RESV;
    #define NB(off_kb) (R + (size_t)(off_kb) * 1024 * ncap)

    bf16*  h0    = (bf16*)NB(0);      // [0,32)
    bf16*  c1o   = (bf16*)NB(32);     // [32,64)
    bf16*  c2o   = (bf16*)NB(64);     // [64,96)
    bf16*  c3o   = (bf16*)NB(96);     // [96,128)
    bf16*  g1p   = (bf16*)NB(128);    // [128,192)  pos|neg sums (64 KB/node)
    bf16*  m1c1o = (bf16*)NB(0);      // [0,64)
    bf16*  m1c2o = (bf16*)NB(64);     // [64,128)
    bf16*  m1c3o = (bf16*)NB(128);    // [128,160)
    bf16*  ds1o  = (bf16*)NB(0);      // [0,8)
    bf16*  g2p   = (bf16*)NB(8);      // [8,24)     pos|neg sums (16 KB/node)
    bf16*  m2c1o = (bf16*)NB(24);     // [24,40)
    bf16*  m2c2o = (bf16*)NB(40);     // [40,56)
    bf16*  m2c3o = (bf16*)NB(56);     // [56,64)
    bf16*  ds2o  = (bf16*)NB(64);     // [64,66)
    bf16*  d1o   = (bf16*)NB(66);     // [66,74)
    bf16*  d2o   = (bf16*)NB(74);     // [74,75)

    int nE    = in_sizes[2] / 3;
    int per_g = nE / N_GRAPHS;

    k_build_adj<<<(N_NODES + 63) / 64, 64, 0, stream>>>(edges, per_g, adj_cnt, adj_lst);
    k_init_out<<<1, 64, 0, stream>>>(out, pb);

    k_prep_w<<<dim3(9, 1, 1), 64, 0, stream>>>(c1w,   WF(0), 9,  16);
    k_prep_w<<<dim3(9, 1, 1), 64, 0, stream>>>(c2w,   WF(1), 16, 16);
    k_prep_w<<<dim3(9, 1, 1), 64, 0, stream>>>(c3w,   WF(2), 16, 16);
    k_prep_w<<<dim3(9, 3, 1), 64, 0, stream>>>(m1c1w, WF(3), 48, 32);
    k_prep_w<<<dim3(9, 2, 1), 64, 0, stream>>>(m1c2w, WF(4), 32, 32);
    k_prep_w<<<dim3(9, 2, 1), 64, 0, stream>>>(m1c3w, WF(5), 32, 16);
    k_prep_w<<<dim3(9, 3, 1), 64, 0, stream>>>(m2c1w, WF(6), 48, 32);
    k_prep_w<<<dim3(9, 2, 1), 64, 0, stream>>>(m2c2w, WF(7), 32, 32);
    k_prep_w<<<dim3(9, 2, 1), 64, 0, stream>>>(m2c3w, WF(8), 32, 16);
    k_prep_w<<<dim3(9, 1, 1),  64, 0, stream>>>(ds1w, wt_ds1, 16,  16);
    k_prep_w<<<dim3(9, 1, 1),  64, 0, stream>>>(ds2w, wt_ds2, 16,  16);
    k_prep_w<<<dim3(9, 1, 8),  64, 0, stream>>>(d1w,  wt_d1,  16,  256);
    k_prep_w<<<dim3(9, 16, 4), 64, 0, stream>>>(d2w,  wt_d2,  256, 128);
    k_prep_w<<<dim3(9, 8, 4),  64, 0, stream>>>(d3w,  wt_d3,  128, 128);

    for (int nb = 0; nb < N_NODES; nb += ncap) {
        int nc = (N_NODES - nb < ncap) ? (N_NODES - nb) : ncap;
        int ng = nc / 16;

        k_embed<<<nc, 256, 0, stream>>>(x, t, w_t, b_t, h0, nb);

        k_conv_mfma<1024, 1, 16, 1, false><<<nc, 256, 0, stream>>>(h0,  nullptr, WF(0), c1b, c1o);
        k_conv_mfma<1024, 1, 16, 1, false><<<nc, 256, 0, stream>>>(c1o, nullptr, WF(1), c2b, c2o);
        k_conv_mfma<1024, 1, 16, 1, false><<<nc, 256, 0, stream>>>(c2o, nullptr, WF(2), c3b, c3o);

        k_gather2<1024><<<dim3(ng, 16), 256, 0, stream>>>(c3o, adj_cnt, adj_lst, g1p, nb);
        k_conv_mfma<1024, 3, 32, 0, true><<<nc, 256, 0, stream>>>(c3o, g1p, WF(3), m1c1b, m1c1o);
        k_conv_mfma<1024, 2, 32, 0, false><<<nc, 256, 0, stream>>>(m1c1o, nullptr, WF(4), m1c2b, m1c2o);
        k_conv_mfma<1024, 2, 16, 0, false><<<nc, 256, 0, stream>>>(m1c2o, nullptr, WF(5), m1c3b, m1c3o);

        k_tail<32, 1, 16, 1, 0><<<nc, 256, 0, stream>>>(
            m1c3o, wt_ds1, ds1b, ds1o, nullptr, nullptr, nullptr, nc, nb);

        k_gather2<256><<<dim3(ng, 4), 256, 0, stream>>>(ds1o, adj_cnt, adj_lst, g2p, nb);
        k_conv_mfma<256, 3, 32, 0, true><<<nc, 256, 0, stream>>>(ds1o, g2p, WF(6), m2c1b, m2c1o);
        k_conv_mfma<256, 2, 32, 0, false><<<nc, 256, 0, stream>>>(m2c1o, nullptr, WF(7), m2c2b, m2c2o);
        k_conv_mfma<256, 2, 16, 0, false><<<nc, 256, 0, stream>>>(m2c2o, nullptr, WF(8), m2c3b, m2c3o);

        k_tail<16, 1, 16, 2, 0><<<(nc + 1) / 2, 256, 0, stream>>>(
            m2c3o, wt_ds2, ds2b, ds2o, nullptr, nullptr, nullptr, nc, nb);
        k_tail<8, 1, 256, 4, 0><<<(nc + 3) / 4, 256, 0, stream>>>(
            ds2o, wt_d1, d1b, d1o, nullptr, nullptr, nullptr, nc, nb);
        k_tail<4, 16, 128, 8, 0><<<(nc + 7) / 8, 256, 0, stream>>>(
            d1o, wt_d2, d2b, d2o, nullptr, nullptr, nullptr, nc, nb);
        k_tail<2, 8, 128, 32, 1><<<(nc + 31) / 32, 256, 0, stream>>>(
            d2o, wt_d3, d3b, nullptr, nd, pw, out, nc, nb);
    }
    #undef NB
    #undef WF
}

// Round 8
// 339.643 us; speedup vs baseline: 7.2104x; 1.3119x over previous
//
#include <hip/hip_runtime.h>
#include <hip/hip_bf16.h>

// ---------------------------------------------------------------------------
// Discriminator (HouseGAN-style), fused-LDS MFMA version (r8).
// Activations: grouped-HWC bf16  [n][ci/8][px][8ci]  (16B chunks per px).
// k_front: embed+c1+c2+c3 fused per image (LDS ping-pong, 64KB).
// k_mid1:  m1c1+m1c2+m1c3+ds1 fused per image (128KB LDS, zero chunk 8192).
// k_mid2:  m2c1+m2c2+m2c3+ds2 fused per image (32KB LDS).
// MFMA layouts (verified r5): A m=lane&31,k=(lane>>5)*8+j; B col=lane&31;
// C col=lane&31,row=(reg&3)+8*(reg>>2)+4*(lane>>5).
// ---------------------------------------------------------------------------

#define N_NODES   1024
#define N_GRAPHS  64

typedef __hip_bfloat16 bf16;
typedef __attribute__((ext_vector_type(8)))  short  short8;
typedef __attribute__((ext_vector_type(16))) float  f32x16;

__device__ __forceinline__ float bf2f(unsigned short s) {
    union { unsigned u; float f; } x; x.u = ((unsigned)s) << 16; return x.f;
}
__device__ __forceinline__ unsigned short f2bf(float f) {
    __hip_bfloat16 h = __float2bfloat16(f);
    return *reinterpret_cast<unsigned short*>(&h);
}
__device__ __forceinline__ uint4 pack8(const float* f) {
    uint4 r;
    r.x = f2bf(f[0]) | ((unsigned)f2bf(f[1]) << 16);
    r.y = f2bf(f[2]) | ((unsigned)f2bf(f[3]) << 16);
    r.z = f2bf(f[4]) | ((unsigned)f2bf(f[5]) << 16);
    r.w = f2bf(f[6]) | ((unsigned)f2bf(f[7]) << 16);
    return r;
}

template<int N>
__device__ __forceinline__ void zacc(f32x16* a) {
    #pragma unroll
    for (int i = 0; i < N; ++i)
        #pragma unroll
        for (int e = 0; e < 16; ++e) a[i][e] = 0.f;
}

// ---- one MFMA phase (16 input ch) of a 3x3 conv over an LDS image ---------
template<int WIN, int WOUT, int STRIDE, int TPW, int TILES>
__device__ __forceinline__ void mfma_phase(
    const short* lds, int inbase, int zch,
    const unsigned short* wfb, int kkstride_sh,
    f32x16* acc, int wid, int lane)
{
    constexpr int NPI = WIN * WIN;
    const int pxl = lane & 31, kg = lane >> 5;
    short8 wfr[9];
    #pragma unroll
    for (int kk = 0; kk < 9; ++kk)
        wfr[kk] = *(const short8*)(wfb + (size_t)kk * kkstride_sh + lane * 8);
    #pragma unroll
    for (int t = 0; t < TPW; ++t) {
        int tile = wid * TPW + t;
        if (TILES < 4 * TPW && tile >= TILES) continue;
        int oy, ox;
        if (WOUT == 32)      { oy = tile;                  ox = pxl;      }
        else if (WOUT == 16) { oy = tile * 2 + (pxl >> 4); ox = pxl & 15; }
        else                 { oy = tile * 4 + (pxl >> 3); ox = pxl & 7;  }
        #pragma unroll
        for (int kk = 0; kk < 9; ++kk) {
            int iy = STRIDE * oy + kk / 3 - 1, ix = STRIDE * ox + kk % 3 - 1;
            bool ok = ((unsigned)iy < (unsigned)WIN) && ((unsigned)ix < (unsigned)WIN);
            int chunk = ok ? (inbase + kg * NPI + iy * WIN + ix) : zch;
            acc[t] = __builtin_amdgcn_mfma_f32_32x32x16_bf16(
                wfr[kk], *(const short8*)(lds + (size_t)chunk * 8), acc[t], 0, 0, 0);
        }
    }
}

// ---- conv epilogue: bias + optional lrelu, write LDS or global grouped ----
template<int WOUT, int COUT, int RELU, int TPW, int TILES, bool TOGLOBAL>
__device__ __forceinline__ void conv_epi(
    short* lds, int outbase, unsigned short* gout,
    const float* __restrict__ bias, const f32x16* acc, int wid, int lane)
{
    constexpr int NPO = WOUT * WOUT;
    const int pxl = lane & 31, kg = lane >> 5;
    #pragma unroll
    for (int t = 0; t < TPW; ++t) {
        int tile = wid * TPW + t;
        if (TILES < 4 * TPW && tile >= TILES) continue;
        int oy, ox;
        if (WOUT == 32)      { oy = tile;                  ox = pxl;      }
        else if (WOUT == 16) { oy = tile * 2 + (pxl >> 4); ox = pxl & 15; }
        else                 { oy = tile * 4 + (pxl >> 3); ox = pxl & 7;  }
        int opx = oy * WOUT + ox;
        #pragma unroll
        for (int q = 0; q < COUT / 8; ++q) {
            unsigned short u[4];
            #pragma unroll
            for (int j = 0; j < 4; ++j) {
                int co = q * 8 + kg * 4 + j;
                float v = acc[t][4 * q + j] + bias[co];
                if (RELU) v = (v >= 0.f) ? v : 0.1f * v;
                u[j] = f2bf(v);
            }
            uint2 pk;
            pk.x = u[0] | ((unsigned)u[1] << 16);
            pk.y = u[2] | ((unsigned)u[3] << 16);
            if constexpr (TOGLOBAL)
                *(uint2*)(gout + ((size_t)q * NPO + opx) * 8 + kg * 4) = pk;
            else
                *(uint2*)(lds + ((size_t)(outbase + q * NPO + opx)) * 8 + kg * 4) = pk;
        }
    }
}

// ---------------- deterministic adjacency build ----------------------------
__global__ __launch_bounds__(64) void k_build_adj(
    const int* __restrict__ edges, int per_g,
    int* __restrict__ cnt, int* __restrict__ lst)
{
    int n = blockIdx.x * 64 + threadIdx.x;
    if (n >= N_NODES) return;
    int g = n >> 4;
    const int* eg = edges + (size_t)g * per_g * 3;
    int c = 0;
    for (int k = 0; k < per_g; ++k) {
        int a = eg[k * 3 + 0];
        int s = eg[k * 3 + 1];
        int b = eg[k * 3 + 2];
        int other = (a == n) ? b : ((b == n) ? a : -1);
        if (other >= 0 && (other >> 4) == g && c < 16) {
            lst[n * 16 + c] = other | ((s < 0) ? (int)0x80000000 : 0);
            ++c;
        }
    }
    cnt[n] = c;
}

// ---------------- weight fragment pre-pack ---------------------------------
__global__ __launch_bounds__(64) void k_prep_w(
    const float* __restrict__ w, unsigned short* __restrict__ wf,
    int Cin, int Cout)
{
    int kk = blockIdx.x, cg = blockIdx.y, m = blockIdx.z;
    int CIG = gridDim.y, MT = gridDim.z;
    int lane = threadIdx.x;
    int co = m * 32 + (lane & 31), kg = lane >> 5;
    float v[8];
    #pragma unroll
    for (int j = 0; j < 8; ++j) {
        int ci = cg * 16 + kg * 8 + j;
        v[j] = (co < Cout && ci < Cin) ? w[((size_t)co * Cin + ci) * 9 + kk] : 0.f;
    }
    *(uint4*)(wf + ((size_t)((kk * CIG + cg) * MT + m) * 64 + lane) * 8) = pack8(v);
}

// ---------------- k_front: embed + c1 + c2 + c3 fused ----------------------
__global__ __launch_bounds__(256) void k_front(
    const float* __restrict__ x, const float* __restrict__ t,
    const float* __restrict__ wt, const float* __restrict__ bt,
    const unsigned short* __restrict__ wf1, const float* __restrict__ b1,
    const unsigned short* __restrict__ wf2, const float* __restrict__ b2,
    const unsigned short* __restrict__ wf3, const float* __restrict__ b3,
    bf16* __restrict__ c3o, int node_base)
{
    // chunks: bufA [0,2048), bufB [2048,4096), zero 4096
    __shared__ __align__(16) short lds[4097 * 8];
    __shared__ float s_t[10];
    const int nl = blockIdx.x, n = node_base + nl, tid = threadIdx.x;
    const int wid = tid >> 6, lane = tid & 63;
    if (tid < 10) s_t[tid] = t[n * 10 + tid];
    if (tid < 8)  lds[4096 * 8 + tid] = 0;
    __syncthreads();

    // embed -> bufA (16 ch: x | 8 t-proj | zeros)
    for (int p = 0; p < 4; ++p) {
        int px = tid + p * 256;
        float ch[16];
        ch[0] = x[(size_t)n * 1024 + px];
        #pragma unroll
        for (int c = 1; c <= 8; ++c) {
            int o = (c - 1) * 1024 + px;
            float a = bt[o];
            const float* wr = wt + (size_t)o * 10;
            #pragma unroll
            for (int k = 0; k < 10; ++k) a += wr[k] * s_t[k];
            ch[c] = a;
        }
        #pragma unroll
        for (int c = 9; c < 16; ++c) ch[c] = 0.f;
        *(uint4*)(lds + (size_t)px * 8)          = pack8(ch);
        *(uint4*)(lds + (size_t)(1024 + px) * 8) = pack8(ch + 8);
    }
    __syncthreads();

    f32x16 acc[8];
    // c1: A -> B, relu
    zacc<8>(acc);
    mfma_phase<32, 32, 1, 8, 32>(lds, 0, 4096, wf1, 512, acc, wid, lane);
    conv_epi<32, 16, 1, 8, 32, false>(lds, 2048, nullptr, b1, acc, wid, lane);
    __syncthreads();
    // c2: B -> A, relu
    zacc<8>(acc);
    mfma_phase<32, 32, 1, 8, 32>(lds, 2048, 4096, wf2, 512, acc, wid, lane);
    conv_epi<32, 16, 1, 8, 32, false>(lds, 0, nullptr, b2, acc, wid, lane);
    __syncthreads();
    // c3: A -> global, relu
    zacc<8>(acc);
    mfma_phase<32, 32, 1, 8, 32>(lds, 0, 4096, wf3, 512, acc, wid, lane);
    conv_epi<32, 16, 1, 8, 32, true>(lds, 0,
        (unsigned short*)c3o + (size_t)nl * 16384, b3, acc, wid, lane);
}

// ---------------- k_mid1: m1c1 + m1c2 + m1c3 + ds1 fused -------------------
__global__ __launch_bounds__(256) void k_mid1(
    const bf16* __restrict__ c3o, const bf16* __restrict__ g1p,
    const unsigned short* __restrict__ wf1, const float* __restrict__ b1,
    const unsigned short* __restrict__ wf2, const float* __restrict__ b2,
    const unsigned short* __restrict__ wf3, const float* __restrict__ b3,
    const unsigned short* __restrict__ wfd, const float* __restrict__ bd,
    bf16* __restrict__ ds1o)
{
    // chunks: stageA [0,2048), stageB [2048,4096), bufX [4096,8192),
    //         bufY [0,4096) (after m1c1), m1c3-out [4096,6144), zero 8192
    __shared__ __align__(16) short lds[8193 * 8];
    const int nl = blockIdx.x, tid = threadIdx.x;
    const int wid = tid >> 6, lane = tid & 63;
    if (tid < 8) lds[8192 * 8 + tid] = 0;

    uint4* l4 = (uint4*)lds;
    const uint4* s0 = (const uint4*)c3o + (size_t)nl * 2048;
    const uint4* s1 = (const uint4*)g1p + (size_t)nl * 4096;
    const uint4* s2 = s1 + 2048;
    for (int i = tid; i < 2048; i += 256) l4[i] = s0[i];
    __syncthreads();

    f32x16 acc[8];
    zacc<8>(acc);
    uint4 pf[8];
    // ph0 (self, in A) || prefetch pos -> B
    #pragma unroll
    for (int r = 0; r < 8; ++r) pf[r] = s1[tid + r * 256];
    mfma_phase<32, 32, 1, 8, 32>(lds, 0, 8192, wf1, 3 * 512, acc, wid, lane);
    #pragma unroll
    for (int r = 0; r < 8; ++r) l4[2048 + tid + r * 256] = pf[r];
    __syncthreads();
    // ph1 (pos, in B) || prefetch neg -> A
    #pragma unroll
    for (int r = 0; r < 8; ++r) pf[r] = s2[tid + r * 256];
    mfma_phase<32, 32, 1, 8, 32>(lds, 2048, 8192, wf1 + 512, 3 * 512, acc, wid, lane);
    #pragma unroll
    for (int r = 0; r < 8; ++r) l4[tid + r * 256] = pf[r];
    __syncthreads();
    // ph2 (neg, in A)
    mfma_phase<32, 32, 1, 8, 32>(lds, 0, 8192, wf1 + 1024, 3 * 512, acc, wid, lane);
    conv_epi<32, 32, 0, 8, 32, false>(lds, 4096, nullptr, b1, acc, wid, lane);
    __syncthreads();

    // m1c2: bufX -> bufY
    zacc<8>(acc);
    mfma_phase<32, 32, 1, 8, 32>(lds, 4096, 8192, wf2,       2 * 512, acc, wid, lane);
    mfma_phase<32, 32, 1, 8, 32>(lds, 6144, 8192, wf2 + 512, 2 * 512, acc, wid, lane);
    conv_epi<32, 32, 0, 8, 32, false>(lds, 0, nullptr, b2, acc, wid, lane);
    __syncthreads();

    // m1c3: bufY -> [4096,6144)
    zacc<8>(acc);
    mfma_phase<32, 32, 1, 8, 32>(lds, 0,    8192, wf3,       2 * 512, acc, wid, lane);
    mfma_phase<32, 32, 1, 8, 32>(lds, 2048, 8192, wf3 + 512, 2 * 512, acc, wid, lane);
    conv_epi<32, 16, 0, 8, 32, false>(lds, 4096, nullptr, b3, acc, wid, lane);
    __syncthreads();

    // ds1: stride-2, relu -> global
    zacc<2>(acc);
    mfma_phase<32, 16, 2, 2, 8>(lds, 4096, 8192, wfd, 512, acc, wid, lane);
    conv_epi<16, 16, 1, 2, 8, true>(lds, 0,
        (unsigned short*)ds1o + (size_t)nl * 4096, bd, acc, wid, lane);
}

// ---------------- k_mid2: m2c1 + m2c2 + m2c3 + ds2 fused -------------------
__global__ __launch_bounds__(256) void k_mid2(
    const bf16* __restrict__ ds1o, const bf16* __restrict__ g2p,
    const unsigned short* __restrict__ wf1, const float* __restrict__ b1,
    const unsigned short* __restrict__ wf2, const float* __restrict__ b2,
    const unsigned short* __restrict__ wf3, const float* __restrict__ b3,
    const unsigned short* __restrict__ wfd, const float* __restrict__ bd,
    bf16* __restrict__ ds2o)
{
    // chunks: stageA [0,512), stageB [512,1024), bufX [1024,2048),
    //         bufY [0,1024), m2c3-out [1024,1536), zero 2048
    __shared__ __align__(16) short lds[2049 * 8];
    const int nl = blockIdx.x, tid = threadIdx.x;
    const int wid = tid >> 6, lane = tid & 63;
    if (tid < 8) lds[2048 * 8 + tid] = 0;

    uint4* l4 = (uint4*)lds;
    const uint4* s0 = (const uint4*)ds1o + (size_t)nl * 512;
    const uint4* s1 = (const uint4*)g2p + (size_t)nl * 1024;
    const uint4* s2 = s1 + 512;
    for (int i = tid; i < 512; i += 256) l4[i] = s0[i];
    __syncthreads();

    f32x16 acc[2];
    zacc<2>(acc);
    uint4 pf[2];
    #pragma unroll
    for (int r = 0; r < 2; ++r) pf[r] = s1[tid + r * 256];
    mfma_phase<16, 16, 1, 2, 8>(lds, 0, 2048, wf1, 3 * 512, acc, wid, lane);
    #pragma unroll
    for (int r = 0; r < 2; ++r) l4[512 + tid + r * 256] = pf[r];
    __syncthreads();
    #pragma unroll
    for (int r = 0; r < 2; ++r) pf[r] = s2[tid + r * 256];
    mfma_phase<16, 16, 1, 2, 8>(lds, 512, 2048, wf1 + 512, 3 * 512, acc, wid, lane);
    #pragma unroll
    for (int r = 0; r < 2; ++r) l4[tid + r * 256] = pf[r];
    __syncthreads();
    mfma_phase<16, 16, 1, 2, 8>(lds, 0, 2048, wf1 + 1024, 3 * 512, acc, wid, lane);
    conv_epi<16, 32, 0, 2, 8, false>(lds, 1024, nullptr, b1, acc, wid, lane);
    __syncthreads();

    zacc<2>(acc);
    mfma_phase<16, 16, 1, 2, 8>(lds, 1024, 2048, wf2,       2 * 512, acc, wid, lane);
    mfma_phase<16, 16, 1, 2, 8>(lds, 1536, 2048, wf2 + 512, 2 * 512, acc, wid, lane);
    conv_epi<16, 32, 0, 2, 8, false>(lds, 0, nullptr, b2, acc, wid, lane);
    __syncthreads();

    zacc<2>(acc);
    mfma_phase<16, 16, 1, 2, 8>(lds, 0,   2048, wf3,       2 * 512, acc, wid, lane);
    mfma_phase<16, 16, 1, 2, 8>(lds, 512, 2048, wf3 + 512, 2 * 512, acc, wid, lane);
    conv_epi<16, 16, 0, 2, 8, false>(lds, 1024, nullptr, b3, acc, wid, lane);
    __syncthreads();

    zacc<2>(acc);
    mfma_phase<16, 8, 2, 1, 2>(lds, 1024, 2048, wfd, 512, acc, wid, lane);
    conv_epi<8, 16, 1, 1, 2, true>(lds, 0,
        (unsigned short*)ds2o + (size_t)nl * 1024, bd, acc, wid, lane);
}

// ---------------- read-once LDS gather: pos/neg sums only ------------------
template<int NPIX>
__global__ __launch_bounds__(256) void k_gather2(
    const bf16* __restrict__ in, const int* __restrict__ cnt,
    const int* __restrict__ lst, bf16* __restrict__ out, int node_base)
{
    constexpr int CPN = 2 * NPIX;
    __shared__ __align__(16) uint4 s_in[16 * 128];
    __shared__ int s_pos[16], s_neg[16];

    const int gl = blockIdx.x, sp = blockIdx.y, tid = threadIdx.x;
    const int gn0 = node_base + gl * 16, nl0 = gl * 16;

    if (tid < 16) {
        int c = cnt[gn0 + tid]; if (c > 16) c = 16;
        int pm = 0, nm = 0;
        for (int k = 0; k < c; ++k) {
            int e = lst[(size_t)(gn0 + tid) * 16 + k];
            int sl = (e & 0x7FFFFFFF) - gn0;
            if ((unsigned)sl < 16u) { if (e < 0) nm |= 1 << sl; else pm |= 1 << sl; }
        }
        s_pos[tid] = pm; s_neg[tid] = nm;
    }
    const uint4* in4 = (const uint4*)in;
    for (int i = tid; i < 2048; i += 256) {
        int srcn = i >> 7, chk = i & 127;
        s_in[i] = in4[(size_t)(nl0 + srcn) * CPN + sp * 128 + chk];
    }
    __syncthreads();

    const int dh = tid >> 7, ch = tid & 127;
    int pm[8], nm[8];
    #pragma unroll
    for (int dl = 0; dl < 8; ++dl) {
        pm[dl] = __builtin_amdgcn_readfirstlane(s_pos[dh * 8 + dl]);
        nm[dl] = __builtin_amdgcn_readfirstlane(s_neg[dh * 8 + dl]);
    }

    float aP[8][8], aN[8][8];
    #pragma unroll
    for (int dl = 0; dl < 8; ++dl)
        #pragma unroll
        for (int j = 0; j < 8; ++j) { aP[dl][j] = 0.f; aN[dl][j] = 0.f; }

    for (int s = 0; s < 16; ++s) {
        union { uint4 v; unsigned short u[8]; } q;
        q.v = s_in[s * 128 + ch];
        float f[8];
        #pragma unroll
        for (int j = 0; j < 8; ++j) f[j] = bf2f(q.u[j]);
        #pragma unroll
        for (int dl = 0; dl < 8; ++dl) {
            if ((pm[dl] >> s) & 1) {
                #pragma unroll
                for (int j = 0; j < 8; ++j) aP[dl][j] += f[j];
            }
            if ((nm[dl] >> s) & 1) {
                #pragma unroll
                for (int j = 0; j < 8; ++j) aN[dl][j] += f[j];
            }
        }
    }

    uint4* out4 = (uint4*)out;
    #pragma unroll
    for (int dl = 0; dl < 8; ++dl) {
        int d = nl0 + dh * 8 + dl;
        out4[((size_t)d * 2 + 0) * CPN + sp * 128 + ch] = pack8(aP[dl]);
        out4[((size_t)d * 2 + 1) * CPN + sp * 128 + ch] = pack8(aN[dl]);
    }
}

// ---------------- MFMA stride-2 conv, images batched into N (d1/d2/d3) -----
template<int HIN, int CIG, int COUT, int IPB, int FUSE_POOL>
__global__ __launch_bounds__(256) void k_tail(
    const bf16* __restrict__ in, const unsigned short* __restrict__ wf,
    const float* __restrict__ bias, bf16* __restrict__ out,
    const int* __restrict__ nd, const float* __restrict__ pw,
    float* __restrict__ pool_out, int nc, int node_base)
{
    constexpr int HOUT = HIN / 2, NPO = HOUT * HOUT, NPI = HIN * HIN;
    constexpr int MT  = (COUT + 31) / 32;
    constexpr int NT  = (IPB * NPO) / 32;
    constexpr int TOT = MT * NT;
    constexpr int TPW = TOT / 4;
    static_assert(TOT % 4 == 0, "tile count must divide over 4 waves");
    constexpr int CHUNKS = IPB * 2 * CIG * NPI;
    __shared__ __align__(16) short sbuf[CHUNKS * 8 + 8];

    const int tid = threadIdx.x, wid = tid >> 6, lane = tid & 63;
    const int col = lane & 31, kg = lane >> 5;
    const int img0 = blockIdx.x * IPB;

    {
        const uint4* src = (const uint4*)in + (size_t)img0 * (2 * CIG * NPI);
        uint4* dst = (uint4*)sbuf;
        int nav = nc - img0; if (nav > IPB) nav = IPB;
        int nch = nav * 2 * CIG * NPI;
        uint4 z = {0, 0, 0, 0};
        for (int i = tid; i < CHUNKS; i += 256) dst[i] = (i < nch) ? src[i] : z;
        if (tid < 8) sbuf[CHUNKS * 8 + tid] = 0;
    }
    __syncthreads();

    int imgb[TPW], poff[TPW][9];
    #pragma unroll
    for (int t = 0; t < TPW; ++t) {
        int tl = wid + 4 * t;
        int n  = tl % NT;
        int idx = n * 32 + col;
        int img = idx / NPO, px = idx % NPO;
        imgb[t] = img * (2 * CIG * NPI);
        int oy = px / HOUT, ox = px % HOUT;
        #pragma unroll
        for (int kk = 0; kk < 9; ++kk) {
            int iy = 2 * oy + kk / 3 - 1, ix = 2 * ox + kk % 3 - 1;
            bool ok = ((unsigned)iy < (unsigned)HIN) && ((unsigned)ix < (unsigned)HIN);
            poff[t][kk] = ok ? (iy * HIN + ix) : -1;
        }
    }

    f32x16 acc[TPW];
    #pragma unroll
    for (int t = 0; t < TPW; ++t)
        #pragma unroll
        for (int e = 0; e < 16; ++e) acc[t][e] = 0.f;

    for (int cig = 0; cig < CIG; ++cig) {
        #pragma unroll
        for (int t = 0; t < TPW; ++t) {
            int m = (wid + 4 * t) / NT;
            #pragma unroll
            for (int kk = 0; kk < 9; ++kk) {
                short8 wfr = *(const short8*)(wf +
                    ((size_t)((kk * CIG + cig) * MT + m) * 64 + lane) * 8);
                int chunk = (poff[t][kk] >= 0)
                          ? imgb[t] + (cig * 2 + kg) * NPI + poff[t][kk]
                          : CHUNKS;
                acc[t] = __builtin_amdgcn_mfma_f32_32x32x16_bf16(
                            wfr, *(const short8*)(sbuf + chunk * 8), acc[t], 0, 0, 0);
            }
        }
    }

    #pragma unroll
    for (int t = 0; t < TPW; ++t) {
        int tl = wid + 4 * t;
        int m = tl / NT, n = tl % NT;
        int idx = n * 32 + col;
        int img = idx / NPO, px = idx % NPO;
        bool live = (img0 + img) < nc;
        if (FUSE_POOL) {
            float part = 0.f;
            #pragma unroll
            for (int r = 0; r < 16; ++r) {
                int co = m * 32 + (r & 3) + 8 * (r >> 2) + 4 * kg;
                float v = acc[t][r] + bias[co];
                v = (v >= 0.f) ? v : 0.1f * v;
                part += v * pw[co];
            }
            part += __shfl_xor(part, 32, 64);
            if (kg == 0 && live) {
                int g = nd[node_base + img0 + img];
                if (g < 0) g = 0; if (g >= N_GRAPHS) g = N_GRAPHS - 1;
                atomicAdd(&pool_out[g], part);
            }
        } else if (live) {
            unsigned short* outp = (unsigned short*)out;
            #pragma unroll
            for (int q = 0; q < 4; ++q) {
                if (m * 32 + q * 8 < COUT) {
                    unsigned short u[4];
                    #pragma unroll
                    for (int j = 0; j < 4; ++j) {
                        int co = m * 32 + q * 8 + kg * 4 + j;
                        float v = acc[t][4 * q + j] + bias[co];
                        v = (v >= 0.f) ? v : 0.1f * v;
                        u[j] = f2bf(v);
                    }
                    uint2 pk;
                    pk.x = u[0] | ((unsigned)u[1] << 16);
                    pk.y = u[2] | ((unsigned)u[3] << 16);
                    *(uint2*)(outp + (((size_t)(img0 + img) * (COUT / 8)
                              + (m * 4 + q)) * NPO + px) * 8 + kg * 4) = pk;
                }
            }
        }
    }
}

// ---------------- head init -------------------------------------------------
__global__ void k_init_out(float* out, const float* __restrict__ pb)
{
    int i = threadIdx.x;
    if (i < N_GRAPHS) out[i] = pb[0];
}

// ---------------------------------------------------------------------------
extern "C" void kernel_launch(void* const* d_in, const int* in_sizes, int n_in,
                              void* d_out, int out_size, void* d_ws, size_t ws_size,
                              hipStream_t stream)
{
    const float* x     = (const float*)d_in[0];
    const float* t     = (const float*)d_in[1];
    const int*   edges = (const int*)d_in[2];
    const int*   nd    = (const int*)d_in[3];
    const float* w_t   = (const float*)d_in[4];
    const float* b_t   = (const float*)d_in[5];
    const float* c1w   = (const float*)d_in[6];
    const float* c1b   = (const float*)d_in[7];
    const float* c2w   = (const float*)d_in[8];
    const float* c2b   = (const float*)d_in[9];
    const float* c3w   = (const float*)d_in[10];
    const float* c3b   = (const float*)d_in[11];
    const float* m1c1w = (const float*)d_in[12];
    const float* m1c1b = (const float*)d_in[13];
    const float* m1c2w = (const float*)d_in[14];
    const float* m1c2b = (const float*)d_in[15];
    const float* m1c3w = (const float*)d_in[16];
    const float* m1c3b = (const float*)d_in[17];
    const float* ds1w  = (const float*)d_in[18];
    const float* ds1b  = (const float*)d_in[19];
    const float* m2c1w = (const float*)d_in[20];
    const float* m2c1b = (const float*)d_in[21];
    const float* m2c2w = (const float*)d_in[22];
    const float* m2c2b = (const float*)d_in[23];
    const float* m2c3w = (const float*)d_in[24];
    const float* m2c3b = (const float*)d_in[25];
    const float* ds2w  = (const float*)d_in[26];
    const float* ds2b  = (const float*)d_in[27];
    const float* d1w   = (const float*)d_in[28];
    const float* d1b   = (const float*)d_in[29];
    const float* d2w   = (const float*)d_in[30];
    const float* d2b   = (const float*)d_in[31];
    const float* d3w   = (const float*)d_in[32];
    const float* d3b   = (const float*)d_in[33];
    const float* pw    = (const float*)d_in[34];
    const float* pb    = (const float*)d_in[35];
    float* out = (float*)d_out;

    uint8_t* ws = (uint8_t*)d_ws;
    int* adj_cnt = (int*)ws;                         // [0, 4K)
    int* adj_lst = (int*)(ws + 4096);                // [4K, 68K)
    #define WF(i)  ((unsigned short*)(ws + (128u << 10) + (size_t)(i) * 32768))
    unsigned short* wt_ds1 = (unsigned short*)(ws + (416u  << 10));
    unsigned short* wt_ds2 = (unsigned short*)(ws + (428u  << 10));
    unsigned short* wt_d1  = (unsigned short*)(ws + (440u  << 10));
    unsigned short* wt_d2  = (unsigned short*)(ws + (512u  << 10));
    unsigned short* wt_d3  = (unsigned short*)(ws + (1088u << 10));

    // ---- adaptive chunking: liveness-packed pool, 120 KiB per node --------
    const size_t RESV = 2ull << 20;
    size_t avail = (ws_size > RESV) ? ws_size - RESV : 0;
    int ncap = (int)(avail / (120 * 1024));
    ncap = (ncap / 16) * 16;
    if (ncap < 16) ncap = 16;
    if (ncap > N_NODES) ncap = N_NODES;
    uint8_t* R = ws + RESV;
    #define NB(off_kb) (R + (size_t)(off_kb) * 1024 * ncap)

    bf16*  c3o  = (bf16*)NB(0);     // [0,32)
    bf16*  g1p  = (bf16*)NB(32);    // [32,96)
    bf16*  ds1o = (bf16*)NB(96);    // [96,104)
    bf16*  g2p  = (bf16*)NB(104);   // [104,120)
    bf16*  ds2o = (bf16*)NB(0);     // [0,2)    (c3o/g1p dead)
    bf16*  d1o  = (bf16*)NB(2);     // [2,10)
    bf16*  d2o  = (bf16*)NB(10);    // [10,11)

    int nE    = in_sizes[2] / 3;
    int per_g = nE / N_GRAPHS;

    k_build_adj<<<(N_NODES + 63) / 64, 64, 0, stream>>>(edges, per_g, adj_cnt, adj_lst);
    k_init_out<<<1, 64, 0, stream>>>(out, pb);

    k_prep_w<<<dim3(9, 1, 1), 64, 0, stream>>>(c1w,   WF(0), 9,  16);
    k_prep_w<<<dim3(9, 1, 1), 64, 0, stream>>>(c2w,   WF(1), 16, 16);
    k_prep_w<<<dim3(9, 1, 1), 64, 0, stream>>>(c3w,   WF(2), 16, 16);
    k_prep_w<<<dim3(9, 3, 1), 64, 0, stream>>>(m1c1w, WF(3), 48, 32);
    k_prep_w<<<dim3(9, 2, 1), 64, 0, stream>>>(m1c2w, WF(4), 32, 32);
    k_prep_w<<<dim3(9, 2, 1), 64, 0, stream>>>(m1c3w, WF(5), 32, 16);
    k_prep_w<<<dim3(9, 3, 1), 64, 0, stream>>>(m2c1w, WF(6), 48, 32);
    k_prep_w<<<dim3(9, 2, 1), 64, 0, stream>>>(m2c2w, WF(7), 32, 32);
    k_prep_w<<<dim3(9, 2, 1), 64, 0, stream>>>(m2c3w, WF(8), 32, 16);
    k_prep_w<<<dim3(9, 1, 1),  64, 0, stream>>>(ds1w, wt_ds1, 16,  16);
    k_prep_w<<<dim3(9, 1, 1),  64, 0, stream>>>(ds2w, wt_ds2, 16,  16);
    k_prep_w<<<dim3(9, 1, 8),  64, 0, stream>>>(d1w,  wt_d1,  16,  256);
    k_prep_w<<<dim3(9, 16, 4), 64, 0, stream>>>(d2w,  wt_d2,  256, 128);
    k_prep_w<<<dim3(9, 8, 4),  64, 0, stream>>>(d3w,  wt_d3,  128, 128);

    for (int nb = 0; nb < N_NODES; nb += ncap) {
        int nc = (N_NODES - nb < ncap) ? (N_NODES - nb) : ncap;
        int ng = nc / 16;

        k_front<<<nc, 256, 0, stream>>>(x, t, w_t, b_t,
            WF(0), c1b, WF(1), c2b, WF(2), c3b, c3o, nb);

        k_gather2<1024><<<dim3(ng, 16), 256, 0, stream>>>(c3o, adj_cnt, adj_lst, g1p, nb);

        k_mid1<<<nc, 256, 0, stream>>>(c3o, g1p,
            WF(3), m1c1b, WF(4), m1c2b, WF(5), m1c3b, wt_ds1, ds1b, ds1o);

        k_gather2<256><<<dim3(ng, 4), 256, 0, stream>>>(ds1o, adj_cnt, adj_lst, g2p, nb);

        k_mid2<<<nc, 256, 0, stream>>>(ds1o, g2p,
            WF(6), m2c1b, WF(7), m2c2b, WF(8), m2c3b, wt_ds2, ds2b, ds2o);

        k_tail<8, 1, 256, 4, 0><<<(nc + 3) / 4, 256, 0, stream>>>(
            ds2o, wt_d1, d1b, d1o, nullptr, nullptr, nullptr, nc, nb);
        k_tail<4, 16, 128, 8, 0><<<(nc + 7) / 8, 256, 0, stream>>>(
            d1o, wt_d2, d2b, d2o, nullptr, nullptr, nullptr, nc, nb);
        k_tail<2, 8, 128, 32, 1><<<(nc + 31) / 32, 256, 0, stream>>>(
            d2o, wt_d3, d3b, nullptr, nd, pw, out, nc, nb);
    }
    #undef NB
    #undef WF
}

// Round 9
// 333.862 us; speedup vs baseline: 7.3352x; 1.0173x over previous
//
#include <hip/hip_runtime.h>
#include <hip/hip_bf16.h>

// ---------------------------------------------------------------------------
// Discriminator (HouseGAN-style), fused-LDS MFMA version (r9: 8-wave blocks).
// Activations: grouped-HWC bf16  [n][ci/8][px][8ci]  (16B chunks per px).
// k_front: embed+c1+c2+c3 fused per image (512 thr, 64.5KB LDS).
// k_mid1:  m1c1+m1c2+m1c3+ds1 fused per image (512 thr, 128.5KB LDS).
// k_mid2:  m2c1+m2c2+m2c3+ds2 fused per image (512 thr, 32.1KB LDS).
// MFMA layouts (verified r5): A m=lane&31,k=(lane>>5)*8+j; B col=lane&31;
// C col=lane&31,row=(reg&3)+8*(reg>>2)+4*(lane>>5).
// ---------------------------------------------------------------------------

#define N_NODES   1024
#define N_GRAPHS  64

typedef __hip_bfloat16 bf16;
typedef __attribute__((ext_vector_type(8)))  short  short8;
typedef __attribute__((ext_vector_type(16))) float  f32x16;

__device__ __forceinline__ float bf2f(unsigned short s) {
    union { unsigned u; float f; } x; x.u = ((unsigned)s) << 16; return x.f;
}
__device__ __forceinline__ unsigned short f2bf(float f) {
    __hip_bfloat16 h = __float2bfloat16(f);
    return *reinterpret_cast<unsigned short*>(&h);
}
__device__ __forceinline__ uint4 pack8(const float* f) {
    uint4 r;
    r.x = f2bf(f[0]) | ((unsigned)f2bf(f[1]) << 16);
    r.y = f2bf(f[2]) | ((unsigned)f2bf(f[3]) << 16);
    r.z = f2bf(f[4]) | ((unsigned)f2bf(f[5]) << 16);
    r.w = f2bf(f[6]) | ((unsigned)f2bf(f[7]) << 16);
    return r;
}

template<int N>
__device__ __forceinline__ void zacc(f32x16* a) {
    #pragma unroll
    for (int i = 0; i < N; ++i)
        #pragma unroll
        for (int e = 0; e < 16; ++e) a[i][e] = 0.f;
}

// ---- one MFMA phase (16 input ch) of a 3x3 conv over an LDS image ---------
// NW waves; wave `wid` owns tiles wid*TPW .. wid*TPW+TPW-1 (guarded by TILES).
template<int WIN, int WOUT, int STRIDE, int TPW, int TILES, int NW>
__device__ __forceinline__ void mfma_phase(
    const short* lds, int inbase, int zch,
    const unsigned short* wfb, int kkstride_sh,
    f32x16* acc, int wid, int lane)
{
    constexpr int NPI = WIN * WIN;
    const int pxl = lane & 31, kg = lane >> 5;
    short8 wfr[9];
    #pragma unroll
    for (int kk = 0; kk < 9; ++kk)
        wfr[kk] = *(const short8*)(wfb + (size_t)kk * kkstride_sh + lane * 8);
    #pragma unroll
    for (int t = 0; t < TPW; ++t) {
        int tile = wid * TPW + t;
        if (NW * TPW > TILES && tile >= TILES) continue;
        int oy, ox;
        if (WOUT == 32)      { oy = tile;                  ox = pxl;      }
        else if (WOUT == 16) { oy = tile * 2 + (pxl >> 4); ox = pxl & 15; }
        else                 { oy = tile * 4 + (pxl >> 3); ox = pxl & 7;  }
        #pragma unroll
        for (int kk = 0; kk < 9; ++kk) {
            int iy = STRIDE * oy + kk / 3 - 1, ix = STRIDE * ox + kk % 3 - 1;
            bool ok = ((unsigned)iy < (unsigned)WIN) && ((unsigned)ix < (unsigned)WIN);
            int chunk = ok ? (inbase + kg * NPI + iy * WIN + ix) : zch;
            acc[t] = __builtin_amdgcn_mfma_f32_32x32x16_bf16(
                wfr[kk], *(const short8*)(lds + (size_t)chunk * 8), acc[t], 0, 0, 0);
        }
    }
}

// ---- conv epilogue: bias + optional lrelu, write LDS or global grouped ----
template<int WOUT, int COUT, int RELU, int TPW, int TILES, int NW, bool TOGLOBAL>
__device__ __forceinline__ void conv_epi(
    short* lds, int outbase, unsigned short* gout,
    const float* __restrict__ bias, const f32x16* acc, int wid, int lane)
{
    constexpr int NPO = WOUT * WOUT;
    const int pxl = lane & 31, kg = lane >> 5;
    #pragma unroll
    for (int t = 0; t < TPW; ++t) {
        int tile = wid * TPW + t;
        if (NW * TPW > TILES && tile >= TILES) continue;
        int oy, ox;
        if (WOUT == 32)      { oy = tile;                  ox = pxl;      }
        else if (WOUT == 16) { oy = tile * 2 + (pxl >> 4); ox = pxl & 15; }
        else                 { oy = tile * 4 + (pxl >> 3); ox = pxl & 7;  }
        int opx = oy * WOUT + ox;
        #pragma unroll
        for (int q = 0; q < COUT / 8; ++q) {
            unsigned short u[4];
            #pragma unroll
            for (int j = 0; j < 4; ++j) {
                int co = q * 8 + kg * 4 + j;
                float v = acc[t][4 * q + j] + bias[co];
                if (RELU) v = (v >= 0.f) ? v : 0.1f * v;
                u[j] = f2bf(v);
            }
            uint2 pk;
            pk.x = u[0] | ((unsigned)u[1] << 16);
            pk.y = u[2] | ((unsigned)u[3] << 16);
            if constexpr (TOGLOBAL)
                *(uint2*)(gout + ((size_t)q * NPO + opx) * 8 + kg * 4) = pk;
            else
                *(uint2*)(lds + ((size_t)(outbase + q * NPO + opx)) * 8 + kg * 4) = pk;
        }
    }
}

// ---------------- deterministic adjacency build ----------------------------
__global__ __launch_bounds__(64) void k_build_adj(
    const int* __restrict__ edges, int per_g,
    int* __restrict__ cnt, int* __restrict__ lst)
{
    int n = blockIdx.x * 64 + threadIdx.x;
    if (n >= N_NODES) return;
    int g = n >> 4;
    const int* eg = edges + (size_t)g * per_g * 3;
    int c = 0;
    for (int k = 0; k < per_g; ++k) {
        int a = eg[k * 3 + 0];
        int s = eg[k * 3 + 1];
        int b = eg[k * 3 + 2];
        int other = (a == n) ? b : ((b == n) ? a : -1);
        if (other >= 0 && (other >> 4) == g && c < 16) {
            lst[n * 16 + c] = other | ((s < 0) ? (int)0x80000000 : 0);
            ++c;
        }
    }
    cnt[n] = c;
}

// ---------------- weight fragment pre-pack ---------------------------------
__global__ __launch_bounds__(64) void k_prep_w(
    const float* __restrict__ w, unsigned short* __restrict__ wf,
    int Cin, int Cout)
{
    int kk = blockIdx.x, cg = blockIdx.y, m = blockIdx.z;
    int CIG = gridDim.y, MT = gridDim.z;
    int lane = threadIdx.x;
    int co = m * 32 + (lane & 31), kg = lane >> 5;
    float v[8];
    #pragma unroll
    for (int j = 0; j < 8; ++j) {
        int ci = cg * 16 + kg * 8 + j;
        v[j] = (co < Cout && ci < Cin) ? w[((size_t)co * Cin + ci) * 9 + kk] : 0.f;
    }
    *(uint4*)(wf + ((size_t)((kk * CIG + cg) * MT + m) * 64 + lane) * 8) = pack8(v);
}

// ---------------- k_front: embed + c1 + c2 + c3 fused (8 waves) ------------
__global__ __launch_bounds__(512) void k_front(
    const float* __restrict__ x, const float* __restrict__ t,
    const float* __restrict__ wt, const float* __restrict__ bt,
    const unsigned short* __restrict__ wf1, const float* __restrict__ b1,
    const unsigned short* __restrict__ wf2, const float* __restrict__ b2,
    const unsigned short* __restrict__ wf3, const float* __restrict__ b3,
    bf16* __restrict__ c3o, int node_base)
{
    // chunks: bufA [0,2048), bufB [2048,4096), zero 4096
    __shared__ __align__(16) short lds[4097 * 8];
    __shared__ float s_t[10];
    const int nl = blockIdx.x, n = node_base + nl, tid = threadIdx.x;
    const int wid = tid >> 6, lane = tid & 63;
    if (tid < 10) s_t[tid] = t[n * 10 + tid];
    if (tid < 8)  lds[4096 * 8 + tid] = 0;
    __syncthreads();

    // embed -> bufA (16 ch: x | 8 t-proj | zeros)
    #pragma unroll
    for (int p = 0; p < 2; ++p) {
        int px = tid + p * 512;
        float ch[16];
        ch[0] = x[(size_t)n * 1024 + px];
        #pragma unroll
        for (int c = 1; c <= 8; ++c) {
            int o = (c - 1) * 1024 + px;
            float a = bt[o];
            const float* wr = wt + (size_t)o * 10;
            #pragma unroll
            for (int k = 0; k < 10; ++k) a += wr[k] * s_t[k];
            ch[c] = a;
        }
        #pragma unroll
        for (int c = 9; c < 16; ++c) ch[c] = 0.f;
        *(uint4*)(lds + (size_t)px * 8)          = pack8(ch);
        *(uint4*)(lds + (size_t)(1024 + px) * 8) = pack8(ch + 8);
    }
    __syncthreads();

    f32x16 acc[4];
    // c1: A -> B, relu
    zacc<4>(acc);
    mfma_phase<32, 32, 1, 4, 32, 8>(lds, 0, 4096, wf1, 512, acc, wid, lane);
    conv_epi<32, 16, 1, 4, 32, 8, false>(lds, 2048, nullptr, b1, acc, wid, lane);
    __syncthreads();
    // c2: B -> A, relu
    zacc<4>(acc);
    mfma_phase<32, 32, 1, 4, 32, 8>(lds, 2048, 4096, wf2, 512, acc, wid, lane);
    conv_epi<32, 16, 1, 4, 32, 8, false>(lds, 0, nullptr, b2, acc, wid, lane);
    __syncthreads();
    // c3: A -> global, relu
    zacc<4>(acc);
    mfma_phase<32, 32, 1, 4, 32, 8>(lds, 0, 4096, wf3, 512, acc, wid, lane);
    conv_epi<32, 16, 1, 4, 32, 8, true>(lds, 0,
        (unsigned short*)c3o + (size_t)nl * 16384, b3, acc, wid, lane);
}

// ---------------- k_mid1: m1c1 + m1c2 + m1c3 + ds1 fused (8 waves) ---------
__global__ __launch_bounds__(512) void k_mid1(
    const bf16* __restrict__ c3o, const bf16* __restrict__ g1p,
    const unsigned short* __restrict__ wf1, const float* __restrict__ b1,
    const unsigned short* __restrict__ wf2, const float* __restrict__ b2,
    const unsigned short* __restrict__ wf3, const float* __restrict__ b3,
    const unsigned short* __restrict__ wfd, const float* __restrict__ bd,
    bf16* __restrict__ ds1o)
{
    // chunks: stageA [0,2048), stageB [2048,4096), bufX [4096,8192),
    //         bufY [0,4096) (after m1c1), m1c3-out [4096,6144), zero 8192
    __shared__ __align__(16) short lds[8193 * 8];
    const int nl = blockIdx.x, tid = threadIdx.x;
    const int wid = tid >> 6, lane = tid & 63;
    if (tid < 8) lds[8192 * 8 + tid] = 0;

    uint4* l4 = (uint4*)lds;
    const uint4* s0 = (const uint4*)c3o + (size_t)nl * 2048;
    const uint4* s1 = (const uint4*)g1p + (size_t)nl * 4096;
    const uint4* s2 = s1 + 2048;
    #pragma unroll
    for (int r = 0; r < 4; ++r) l4[tid + r * 512] = s0[tid + r * 512];
    __syncthreads();

    f32x16 acc[4];
    zacc<4>(acc);
    uint4 pf[4];
    // ph0 (self, in A) || prefetch pos -> B
    #pragma unroll
    for (int r = 0; r < 4; ++r) pf[r] = s1[tid + r * 512];
    mfma_phase<32, 32, 1, 4, 32, 8>(lds, 0, 8192, wf1, 3 * 512, acc, wid, lane);
    #pragma unroll
    for (int r = 0; r < 4; ++r) l4[2048 + tid + r * 512] = pf[r];
    __syncthreads();
    // ph1 (pos, in B) || prefetch neg -> A
    #pragma unroll
    for (int r = 0; r < 4; ++r) pf[r] = s2[tid + r * 512];
    mfma_phase<32, 32, 1, 4, 32, 8>(lds, 2048, 8192, wf1 + 512, 3 * 512, acc, wid, lane);
    #pragma unroll
    for (int r = 0; r < 4; ++r) l4[tid + r * 512] = pf[r];
    __syncthreads();
    // ph2 (neg, in A)
    mfma_phase<32, 32, 1, 4, 32, 8>(lds, 0, 8192, wf1 + 1024, 3 * 512, acc, wid, lane);
    conv_epi<32, 32, 0, 4, 32, 8, false>(lds, 4096, nullptr, b1, acc, wid, lane);
    __syncthreads();

    // m1c2: bufX -> bufY
    zacc<4>(acc);
    mfma_phase<32, 32, 1, 4, 32, 8>(lds, 4096, 8192, wf2,       2 * 512, acc, wid, lane);
    mfma_phase<32, 32, 1, 4, 32, 8>(lds, 6144, 8192, wf2 + 512, 2 * 512, acc, wid, lane);
    conv_epi<32, 32, 0, 4, 32, 8, false>(lds, 0, nullptr, b2, acc, wid, lane);
    __syncthreads();

    // m1c3: bufY -> [4096,6144)
    zacc<4>(acc);
    mfma_phase<32, 32, 1, 4, 32, 8>(lds, 0,    8192, wf3,       2 * 512, acc, wid, lane);
    mfma_phase<32, 32, 1, 4, 32, 8>(lds, 2048, 8192, wf3 + 512, 2 * 512, acc, wid, lane);
    conv_epi<32, 16, 0, 4, 32, 8, false>(lds, 4096, nullptr, b3, acc, wid, lane);
    __syncthreads();

    // ds1: stride-2, relu -> global
    zacc<1>(acc);
    mfma_phase<32, 16, 2, 1, 8, 8>(lds, 4096, 8192, wfd, 512, acc, wid, lane);
    conv_epi<16, 16, 1, 1, 8, 8, true>(lds, 0,
        (unsigned short*)ds1o + (size_t)nl * 4096, bd, acc, wid, lane);
}

// ---------------- k_mid2: m2c1 + m2c2 + m2c3 + ds2 fused (8 waves) ---------
__global__ __launch_bounds__(512) void k_mid2(
    const bf16* __restrict__ ds1o, const bf16* __restrict__ g2p,
    const unsigned short* __restrict__ wf1, const float* __restrict__ b1,
    const unsigned short* __restrict__ wf2, const float* __restrict__ b2,
    const unsigned short* __restrict__ wf3, const float* __restrict__ b3,
    const unsigned short* __restrict__ wfd, const float* __restrict__ bd,
    bf16* __restrict__ ds2o)
{
    // chunks: stageA [0,512), stageB [512,1024), bufX [1024,2048),
    //         bufY [0,1024), m2c3-out [1024,1536), zero 2048
    __shared__ __align__(16) short lds[2049 * 8];
    const int nl = blockIdx.x, tid = threadIdx.x;
    const int wid = tid >> 6, lane = tid & 63;
    if (tid < 8) lds[2048 * 8 + tid] = 0;

    uint4* l4 = (uint4*)lds;
    const uint4* s0 = (const uint4*)ds1o + (size_t)nl * 512;
    const uint4* s1 = (const uint4*)g2p + (size_t)nl * 1024;
    const uint4* s2 = s1 + 512;
    l4[tid] = s0[tid];
    __syncthreads();

    f32x16 acc[1];
    zacc<1>(acc);
    uint4 pf;
    pf = s1[tid];
    mfma_phase<16, 16, 1, 1, 8, 8>(lds, 0, 2048, wf1, 3 * 512, acc, wid, lane);
    l4[512 + tid] = pf;
    __syncthreads();
    pf = s2[tid];
    mfma_phase<16, 16, 1, 1, 8, 8>(lds, 512, 2048, wf1 + 512, 3 * 512, acc, wid, lane);
    l4[tid] = pf;
    __syncthreads();
    mfma_phase<16, 16, 1, 1, 8, 8>(lds, 0, 2048, wf1 + 1024, 3 * 512, acc, wid, lane);
    conv_epi<16, 32, 0, 1, 8, 8, false>(lds, 1024, nullptr, b1, acc, wid, lane);
    __syncthreads();

    zacc<1>(acc);
    mfma_phase<16, 16, 1, 1, 8, 8>(lds, 1024, 2048, wf2,       2 * 512, acc, wid, lane);
    mfma_phase<16, 16, 1, 1, 8, 8>(lds, 1536, 2048, wf2 + 512, 2 * 512, acc, wid, lane);
    conv_epi<16, 32, 0, 1, 8, 8, false>(lds, 0, nullptr, b2, acc, wid, lane);
    __syncthreads();

    zacc<1>(acc);
    mfma_phase<16, 16, 1, 1, 8, 8>(lds, 0,   2048, wf3,       2 * 512, acc, wid, lane);
    mfma_phase<16, 16, 1, 1, 8, 8>(lds, 512, 2048, wf3 + 512, 2 * 512, acc, wid, lane);
    conv_epi<16, 16, 0, 1, 8, 8, false>(lds, 1024, nullptr, b3, acc, wid, lane);
    __syncthreads();

    zacc<1>(acc);
    mfma_phase<16, 8, 2, 1, 2, 8>(lds, 1024, 2048, wfd, 512, acc, wid, lane);
    conv_epi<8, 16, 1, 1, 2, 8, true>(lds, 0,
        (unsigned short*)ds2o + (size_t)nl * 1024, bd, acc, wid, lane);
}

// ---------------- read-once LDS gather: pos/neg sums only ------------------
template<int NPIX>
__global__ __launch_bounds__(256) void k_gather2(
    const bf16* __restrict__ in, const int* __restrict__ cnt,
    const int* __restrict__ lst, bf16* __restrict__ out, int node_base)
{
    constexpr int CPN = 2 * NPIX;
    __shared__ __align__(16) uint4 s_in[16 * 128];
    __shared__ int s_pos[16], s_neg[16];

    const int gl = blockIdx.x, sp = blockIdx.y, tid = threadIdx.x;
    const int gn0 = node_base + gl * 16, nl0 = gl * 16;

    if (tid < 16) {
        int c = cnt[gn0 + tid]; if (c > 16) c = 16;
        int pm = 0, nm = 0;
        for (int k = 0; k < c; ++k) {
            int e = lst[(size_t)(gn0 + tid) * 16 + k];
            int sl = (e & 0x7FFFFFFF) - gn0;
            if ((unsigned)sl < 16u) { if (e < 0) nm |= 1 << sl; else pm |= 1 << sl; }
        }
        s_pos[tid] = pm; s_neg[tid] = nm;
    }
    const uint4* in4 = (const uint4*)in;
    for (int i = tid; i < 2048; i += 256) {
        int srcn = i >> 7, chk = i & 127;
        s_in[i] = in4[(size_t)(nl0 + srcn) * CPN + sp * 128 + chk];
    }
    __syncthreads();

    const int dh = tid >> 7, ch = tid & 127;
    int pm[8], nm[8];
    #pragma unroll
    for (int dl = 0; dl < 8; ++dl) {
        pm[dl] = __builtin_amdgcn_readfirstlane(s_pos[dh * 8 + dl]);
        nm[dl] = __builtin_amdgcn_readfirstlane(s_neg[dh * 8 + dl]);
    }

    float aP[8][8], aN[8][8];
    #pragma unroll
    for (int dl = 0; dl < 8; ++dl)
        #pragma unroll
        for (int j = 0; j < 8; ++j) { aP[dl][j] = 0.f; aN[dl][j] = 0.f; }

    for (int s = 0; s < 16; ++s) {
        union { uint4 v; unsigned short u[8]; } q;
        q.v = s_in[s * 128 + ch];
        float f[8];
        #pragma unroll
        for (int j = 0; j < 8; ++j) f[j] = bf2f(q.u[j]);
        #pragma unroll
        for (int dl = 0; dl < 8; ++dl) {
            if ((pm[dl] >> s) & 1) {
                #pragma unroll
                for (int j = 0; j < 8; ++j) aP[dl][j] += f[j];
            }
            if ((nm[dl] >> s) & 1) {
                #pragma unroll
                for (int j = 0; j < 8; ++j) aN[dl][j] += f[j];
            }
        }
    }

    uint4* out4 = (uint4*)out;
    #pragma unroll
    for (int dl = 0; dl < 8; ++dl) {
        int d = nl0 + dh * 8 + dl;
        out4[((size_t)d * 2 + 0) * CPN + sp * 128 + ch] = pack8(aP[dl]);
        out4[((size_t)d * 2 + 1) * CPN + sp * 128 + ch] = pack8(aN[dl]);
    }
}

// ---------------- MFMA stride-2 conv, images batched into N (d1/d2/d3) -----
template<int HIN, int CIG, int COUT, int IPB, int FUSE_POOL>
__global__ __launch_bounds__(256) void k_tail(
    const bf16* __restrict__ in, const unsigned short* __restrict__ wf,
    const float* __restrict__ bias, bf16* __restrict__ out,
    const int* __restrict__ nd, const float* __restrict__ pw,
    float* __restrict__ pool_out, int nc, int node_base)
{
    constexpr int HOUT = HIN / 2, NPO = HOUT * HOUT, NPI = HIN * HIN;
    constexpr int MT  = (COUT + 31) / 32;
    constexpr int NT  = (IPB * NPO) / 32;
    constexpr int TOT = MT * NT;
    constexpr int TPW = TOT / 4;
    static_assert(TOT % 4 == 0, "tile count must divide over 4 waves");
    constexpr int CHUNKS = IPB * 2 * CIG * NPI;
    __shared__ __align__(16) short sbuf[CHUNKS * 8 + 8];

    const int tid = threadIdx.x, wid = tid >> 6, lane = tid & 63;
    const int col = lane & 31, kg = lane >> 5;
    const int img0 = blockIdx.x * IPB;

    {
        const uint4* src = (const uint4*)in + (size_t)img0 * (2 * CIG * NPI);
        uint4* dst = (uint4*)sbuf;
        int nav = nc - img0; if (nav > IPB) nav = IPB;
        int nch = nav * 2 * CIG * NPI;
        uint4 z = {0, 0, 0, 0};
        for (int i = tid; i < CHUNKS; i += 256) dst[i] = (i < nch) ? src[i] : z;
        if (tid < 8) sbuf[CHUNKS * 8 + tid] = 0;
    }
    __syncthreads();

    int imgb[TPW], poff[TPW][9];
    #pragma unroll
    for (int t = 0; t < TPW; ++t) {
        int tl = wid + 4 * t;
        int n  = tl % NT;
        int idx = n * 32 + col;
        int img = idx / NPO, px = idx % NPO;
        imgb[t] = img * (2 * CIG * NPI);
        int oy = px / HOUT, ox = px % HOUT;
        #pragma unroll
        for (int kk = 0; kk < 9; ++kk) {
            int iy = 2 * oy + kk / 3 - 1, ix = 2 * ox + kk % 3 - 1;
            bool ok = ((unsigned)iy < (unsigned)HIN) && ((unsigned)ix < (unsigned)HIN);
            poff[t][kk] = ok ? (iy * HIN + ix) : -1;
        }
    }

    f32x16 acc[TPW];
    #pragma unroll
    for (int t = 0; t < TPW; ++t)
        #pragma unroll
        for (int e = 0; e < 16; ++e) acc[t][e] = 0.f;

    for (int cig = 0; cig < CIG; ++cig) {
        #pragma unroll
        for (int t = 0; t < TPW; ++t) {
            int m = (wid + 4 * t) / NT;
            #pragma unroll
            for (int kk = 0; kk < 9; ++kk) {
                short8 wfr = *(const short8*)(wf +
                    ((size_t)((kk * CIG + cig) * MT + m) * 64 + lane) * 8);
                int chunk = (poff[t][kk] >= 0)
                          ? imgb[t] + (cig * 2 + kg) * NPI + poff[t][kk]
                          : CHUNKS;
                acc[t] = __builtin_amdgcn_mfma_f32_32x32x16_bf16(
                            wfr, *(const short8*)(sbuf + chunk * 8), acc[t], 0, 0, 0);
            }
        }
    }

    #pragma unroll
    for (int t = 0; t < TPW; ++t) {
        int tl = wid + 4 * t;
        int m = tl / NT, n = tl % NT;
        int idx = n * 32 + col;
        int img = idx / NPO, px = idx % NPO;
        bool live = (img0 + img) < nc;
        if (FUSE_POOL) {
            float part = 0.f;
            #pragma unroll
            for (int r = 0; r < 16; ++r) {
                int co = m * 32 + (r & 3) + 8 * (r >> 2) + 4 * kg;
                float v = acc[t][r] + bias[co];
                v = (v >= 0.f) ? v : 0.1f * v;
                part += v * pw[co];
            }
            part += __shfl_xor(part, 32, 64);
            if (kg == 0 && live) {
                int g = nd[node_base + img0 + img];
                if (g < 0) g = 0; if (g >= N_GRAPHS) g = N_GRAPHS - 1;
                atomicAdd(&pool_out[g], part);
            }
        } else if (live) {
            unsigned short* outp = (unsigned short*)out;
            #pragma unroll
            for (int q = 0; q < 4; ++q) {
                if (m * 32 + q * 8 < COUT) {
                    unsigned short u[4];
                    #pragma unroll
                    for (int j = 0; j < 4; ++j) {
                        int co = m * 32 + q * 8 + kg * 4 + j;
                        float v = acc[t][4 * q + j] + bias[co];
                        v = (v >= 0.f) ? v : 0.1f * v;
                        u[j] = f2bf(v);
                    }
                    uint2 pk;
                    pk.x = u[0] | ((unsigned)u[1] << 16);
                    pk.y = u[2] | ((unsigned)u[3] << 16);
                    *(uint2*)(outp + (((size_t)(img0 + img) * (COUT / 8)
                              + (m * 4 + q)) * NPO + px) * 8 + kg * 4) = pk;
                }
            }
        }
    }
}

// ---------------- head init -------------------------------------------------
__global__ void k_init_out(float* out, const float* __restrict__ pb)
{
    int i = threadIdx.x;
    if (i < N_GRAPHS) out[i] = pb[0];
}

// ---------------------------------------------------------------------------
extern "C" void kernel_launch(void* const* d_in, const int* in_sizes, int n_in,
                              void* d_out, int out_size, void* d_ws, size_t ws_size,
                              hipStream_t stream)
{
    const float* x     = (const float*)d_in[0];
    const float* t     = (const float*)d_in[1];
    const int*   edges = (const int*)d_in[2];
    const int*   nd    = (const int*)d_in[3];
    const float* w_t   = (const float*)d_in[4];
    const float* b_t   = (const float*)d_in[5];
    const float* c1w   = (const float*)d_in[6];
    const float* c1b   = (const float*)d_in[7];
    const float* c2w   = (const float*)d_in[8];
    const float* c2b   = (const float*)d_in[9];
    const float* c3w   = (const float*)d_in[10];
    const float* c3b   = (const float*)d_in[11];
    const float* m1c1w = (const float*)d_in[12];
    const float* m1c1b = (const float*)d_in[13];
    const float* m1c2w = (const float*)d_in[14];
    const float* m1c2b = (const float*)d_in[15];
    const float* m1c3w = (const float*)d_in[16];
    const float* m1c3b = (const float*)d_in[17];
    const float* ds1w  = (const float*)d_in[18];
    const float* ds1b  = (const float*)d_in[19];
    const float* m2c1w = (const float*)d_in[20];
    const float* m2c1b = (const float*)d_in[21];
    const float* m2c2w = (const float*)d_in[22];
    const float* m2c2b = (const float*)d_in[23];
    const float* m2c3w = (const float*)d_in[24];
    const float* m2c3b = (const float*)d_in[25];
    const float* ds2w  = (const float*)d_in[26];
    const float* ds2b  = (const float*)d_in[27];
    const float* d1w   = (const float*)d_in[28];
    const float* d1b   = (const float*)d_in[29];
    const float* d2w   = (const float*)d_in[30];
    const float* d2b   = (const float*)d_in[31];
    const float* d3w   = (const float*)d_in[32];
    const float* d3b   = (const float*)d_in[33];
    const float* pw    = (const float*)d_in[34];
    const float* pb    = (const float*)d_in[35];
    float* out = (float*)d_out;

    uint8_t* ws = (uint8_t*)d_ws;
    int* adj_cnt = (int*)ws;                         // [0, 4K)
    int* adj_lst = (int*)(ws + 4096);                // [4K, 68K)
    #define WF(i)  ((unsigned short*)(ws + (128u << 10) + (size_t)(i) * 32768))
    unsigned short* wt_ds1 = (unsigned short*)(ws + (416u  << 10));
    unsigned short* wt_ds2 = (unsigned short*)(ws + (428u  << 10));
    unsigned short* wt_d1  = (unsigned short*)(ws + (440u  << 10));
    unsigned short* wt_d2  = (unsigned short*)(ws + (512u  << 10));
    unsigned short* wt_d3  = (unsigned short*)(ws + (1088u << 10));

    // ---- adaptive chunking: liveness-packed pool, 120 KiB per node --------
    const size_t RESV = 2ull << 20;
    size_t avail = (ws_size > RESV) ? ws_size - RESV : 0;
    int ncap = (int)(avail / (120 * 1024));
    ncap = (ncap / 16) * 16;
    if (ncap < 16) ncap = 16;
    if (ncap > N_NODES) ncap = N_NODES;
    uint8_t* R = ws + RESV;
    #define NB(off_kb) (R + (size_t)(off_kb) * 1024 * ncap)

    bf16*  c3o  = (bf16*)NB(0);     // [0,32)
    bf16*  g1p  = (bf16*)NB(32);    // [32,96)
    bf16*  ds1o = (bf16*)NB(96);    // [96,104)
    bf16*  g2p  = (bf16*)NB(104);   // [104,120)
    bf16*  ds2o = (bf16*)NB(0);     // [0,2)    (c3o/g1p dead)
    bf16*  d1o  = (bf16*)NB(2);     // [2,10)
    bf16*  d2o  = (bf16*)NB(10);    // [10,11)

    int nE    = in_sizes[2] / 3;
    int per_g = nE / N_GRAPHS;

    k_build_adj<<<(N_NODES + 63) / 64, 64, 0, stream>>>(edges, per_g, adj_cnt, adj_lst);
    k_init_out<<<1, 64, 0, stream>>>(out, pb);

    k_prep_w<<<dim3(9, 1, 1), 64, 0, stream>>>(c1w,   WF(0), 9,  16);
    k_prep_w<<<dim3(9, 1, 1), 64, 0, stream>>>(c2w,   WF(1), 16, 16);
    k_prep_w<<<dim3(9, 1, 1), 64, 0, stream>>>(c3w,   WF(2), 16, 16);
    k_prep_w<<<dim3(9, 3, 1), 64, 0, stream>>>(m1c1w, WF(3), 48, 32);
    k_prep_w<<<dim3(9, 2, 1), 64, 0, stream>>>(m1c2w, WF(4), 32, 32);
    k_prep_w<<<dim3(9, 2, 1), 64, 0, stream>>>(m1c3w, WF(5), 32, 16);
    k_prep_w<<<dim3(9, 3, 1), 64, 0, stream>>>(m2c1w, WF(6), 48, 32);
    k_prep_w<<<dim3(9, 2, 1), 64, 0, stream>>>(m2c2w, WF(7), 32, 32);
    k_prep_w<<<dim3(9, 2, 1), 64, 0, stream>>>(m2c3w, WF(8), 32, 16);
    k_prep_w<<<dim3(9, 1, 1),  64, 0, stream>>>(ds1w, wt_ds1, 16,  16);
    k_prep_w<<<dim3(9, 1, 1),  64, 0, stream>>>(ds2w, wt_ds2, 16,  16);
    k_prep_w<<<dim3(9, 1, 8),  64, 0, stream>>>(d1w,  wt_d1,  16,  256);
    k_prep_w<<<dim3(9, 16, 4), 64, 0, stream>>>(d2w,  wt_d2,  256, 128);
    k_prep_w<<<dim3(9, 8, 4),  64, 0, stream>>>(d3w,  wt_d3,  128, 128);

    for (int nb = 0; nb < N_NODES; nb += ncap) {
        int nc = (N_NODES - nb < ncap) ? (N_NODES - nb) : ncap;
        int ng = nc / 16;

        k_front<<<nc, 512, 0, stream>>>(x, t, w_t, b_t,
            WF(0), c1b, WF(1), c2b, WF(2), c3b, c3o, nb);

        k_gather2<1024><<<dim3(ng, 16), 256, 0, stream>>>(c3o, adj_cnt, adj_lst, g1p, nb);

        k_mid1<<<nc, 512, 0, stream>>>(c3o, g1p,
            WF(3), m1c1b, WF(4), m1c2b, WF(5), m1c3b, wt_ds1, ds1b, ds1o);

        k_gather2<256><<<dim3(ng, 4), 256, 0, stream>>>(ds1o, adj_cnt, adj_lst, g2p, nb);

        k_mid2<<<nc, 512, 0, stream>>>(ds1o, g2p,
            WF(6), m2c1b, WF(7), m2c2b, WF(8), m2c3b, wt_ds2, ds2b, ds2o);

        k_tail<8, 1, 256, 4, 0><<<(nc + 3) / 4, 256, 0, stream>>>(
            ds2o, wt_d1, d1b, d1o, nullptr, nullptr, nullptr, nc, nb);
        k_tail<4, 16, 128, 8, 0><<<(nc + 7) / 8, 256, 0, stream>>>(
            d1o, wt_d2, d2b, d2o, nullptr, nullptr, nullptr, nc, nb);
        k_tail<2, 8, 128, 32, 1><<<(nc + 31) / 32, 256, 0, stream>>>(
            d2o, wt_d3, d3b, nullptr, nd, pw, out, nc, nb);
    }
    #undef NB
    #undef WF
}

// Round 10
// 285.284 us; speedup vs baseline: 8.5843x; 1.1703x over previous
//
#include <hip/hip_runtime.h>
#include <hip/hip_bf16.h>

// ---------------------------------------------------------------------------
// Discriminator (HouseGAN-style), fused-LDS MFMA version.
// r10: row-reuse MFMA phases for 32x32 stride-1 convs (18 ds_read_b128 per
// phase per wave instead of 36 — LDS read-throughput was the r9 wall),
// merged weight-prep into one kernel.
// Activations: grouped-HWC bf16  [n][ci/8][px][8ci]  (16B chunks per px).
// MFMA layouts (verified r5): A m=lane&31,k=(lane>>5)*8+j; B col=lane&31;
// C col=lane&31,row=(reg&3)+8*(reg>>2)+4*(lane>>5).
// ---------------------------------------------------------------------------

#define N_NODES   1024
#define N_GRAPHS  64

typedef __hip_bfloat16 bf16;
typedef __attribute__((ext_vector_type(8)))  short  short8;
typedef __attribute__((ext_vector_type(16))) float  f32x16;

__device__ __forceinline__ float bf2f(unsigned short s) {
    union { unsigned u; float f; } x; x.u = ((unsigned)s) << 16; return x.f;
}
__device__ __forceinline__ unsigned short f2bf(float f) {
    __hip_bfloat16 h = __float2bfloat16(f);
    return *reinterpret_cast<unsigned short*>(&h);
}
__device__ __forceinline__ uint4 pack8(const float* f) {
    uint4 r;
    r.x = f2bf(f[0]) | ((unsigned)f2bf(f[1]) << 16);
    r.y = f2bf(f[2]) | ((unsigned)f2bf(f[3]) << 16);
    r.z = f2bf(f[4]) | ((unsigned)f2bf(f[5]) << 16);
    r.w = f2bf(f[6]) | ((unsigned)f2bf(f[7]) << 16);
    return r;
}

template<int N>
__device__ __forceinline__ void zacc(f32x16* a) {
    #pragma unroll
    for (int i = 0; i < N; ++i)
        #pragma unroll
        for (int e = 0; e < 16; ++e) a[i][e] = 0.f;
}

// ---- row-reuse MFMA phase: 32x32 image, stride 1, TPW contiguous rows/wave.
// Each input-row fragment (3 dx shifts) is read ONCE and fired into up to 3
// output-row accumulators (dy taps) -> 18 reads / 36 MFMA per phase-call.
template<int TPW, int NW>
__device__ __forceinline__ void mfma_rr32(
    const short* lds, int inbase, int zch,
    const unsigned short* wfb, int kkstride_sh,
    f32x16* acc, int wid, int lane)
{
    const int pxl = lane & 31, kg = lane >> 5;
    short8 wfr[9];
    #pragma unroll
    for (int kk = 0; kk < 9; ++kk)
        wfr[kk] = *(const short8*)(wfb + (size_t)kk * kkstride_sh + lane * 8);
    const int r0 = wid * TPW;
    #pragma unroll
    for (int ir = 0; ir < TPW + 2; ++ir) {
        int iy = r0 - 1 + ir;
        if (iy < 0 || iy > 31) continue;          // wave-uniform edge skip
        #pragma unroll
        for (int dx = 0; dx < 3; ++dx) {
            int ix = pxl + dx - 1;
            bool ok = (unsigned)ix < 32u;
            int chunk = ok ? (inbase + kg * 1024 + iy * 32 + ix) : zch;
            short8 B = *(const short8*)(lds + (size_t)chunk * 8);
            #pragma unroll
            for (int dy = -1; dy <= 1; ++dy) {
                constexpr int dummy = 0; (void)dummy;
                int a = ir - 1 - dy;               // compile-time per (ir,dy)
                if (a < 0 || a >= TPW) continue;
                acc[a] = __builtin_amdgcn_mfma_f32_32x32x16_bf16(
                    wfr[(dy + 1) * 3 + dx], B, acc[a], 0, 0, 0);
            }
        }
    }
}

// ---- generic MFMA phase (kept for 16x16 images and stride-2 convs) --------
template<int WIN, int WOUT, int STRIDE, int TPW, int TILES, int NW>
__device__ __forceinline__ void mfma_phase(
    const short* lds, int inbase, int zch,
    const unsigned short* wfb, int kkstride_sh,
    f32x16* acc, int wid, int lane)
{
    constexpr int NPI = WIN * WIN;
    const int pxl = lane & 31, kg = lane >> 5;
    short8 wfr[9];
    #pragma unroll
    for (int kk = 0; kk < 9; ++kk)
        wfr[kk] = *(const short8*)(wfb + (size_t)kk * kkstride_sh + lane * 8);
    #pragma unroll
    for (int t = 0; t < TPW; ++t) {
        int tile = wid * TPW + t;
        if (NW * TPW > TILES && tile >= TILES) continue;
        int oy, ox;
        if (WOUT == 32)      { oy = tile;                  ox = pxl;      }
        else if (WOUT == 16) { oy = tile * 2 + (pxl >> 4); ox = pxl & 15; }
        else                 { oy = tile * 4 + (pxl >> 3); ox = pxl & 7;  }
        #pragma unroll
        for (int kk = 0; kk < 9; ++kk) {
            int iy = STRIDE * oy + kk / 3 - 1, ix = STRIDE * ox + kk % 3 - 1;
            bool ok = ((unsigned)iy < (unsigned)WIN) && ((unsigned)ix < (unsigned)WIN);
            int chunk = ok ? (inbase + kg * NPI + iy * WIN + ix) : zch;
            acc[t] = __builtin_amdgcn_mfma_f32_32x32x16_bf16(
                wfr[kk], *(const short8*)(lds + (size_t)chunk * 8), acc[t], 0, 0, 0);
        }
    }
}

// ---- conv epilogue: bias + optional lrelu, write LDS or global grouped ----
template<int WOUT, int COUT, int RELU, int TPW, int TILES, int NW, bool TOGLOBAL>
__device__ __forceinline__ void conv_epi(
    short* lds, int outbase, unsigned short* gout,
    const float* __restrict__ bias, const f32x16* acc, int wid, int lane)
{
    constexpr int NPO = WOUT * WOUT;
    const int pxl = lane & 31, kg = lane >> 5;
    #pragma unroll
    for (int t = 0; t < TPW; ++t) {
        int tile = wid * TPW + t;
        if (NW * TPW > TILES && tile >= TILES) continue;
        int oy, ox;
        if (WOUT == 32)      { oy = tile;                  ox = pxl;      }
        else if (WOUT == 16) { oy = tile * 2 + (pxl >> 4); ox = pxl & 15; }
        else                 { oy = tile * 4 + (pxl >> 3); ox = pxl & 7;  }
        int opx = oy * WOUT + ox;
        #pragma unroll
        for (int q = 0; q < COUT / 8; ++q) {
            unsigned short u[4];
            #pragma unroll
            for (int j = 0; j < 4; ++j) {
                int co = q * 8 + kg * 4 + j;
                float v = acc[t][4 * q + j] + bias[co];
                if (RELU) v = (v >= 0.f) ? v : 0.1f * v;
                u[j] = f2bf(v);
            }
            uint2 pk;
            pk.x = u[0] | ((unsigned)u[1] << 16);
            pk.y = u[2] | ((unsigned)u[3] << 16);
            if constexpr (TOGLOBAL)
                *(uint2*)(gout + ((size_t)q * NPO + opx) * 8 + kg * 4) = pk;
            else
                *(uint2*)(lds + ((size_t)(outbase + q * NPO + opx)) * 8 + kg * 4) = pk;
        }
    }
}

// ---------------- deterministic adjacency build ----------------------------
__global__ __launch_bounds__(64) void k_build_adj(
    const int* __restrict__ edges, int per_g,
    int* __restrict__ cnt, int* __restrict__ lst)
{
    int n = blockIdx.x * 64 + threadIdx.x;
    if (n >= N_NODES) return;
    int g = n >> 4;
    const int* eg = edges + (size_t)g * per_g * 3;
    int c = 0;
    for (int k = 0; k < per_g; ++k) {
        int a = eg[k * 3 + 0];
        int s = eg[k * 3 + 1];
        int b = eg[k * 3 + 2];
        int other = (a == n) ? b : ((b == n) ? a : -1);
        if (other >= 0 && (other >> 4) == g && c < 16) {
            lst[n * 16 + c] = other | ((s < 0) ? (int)0x80000000 : 0);
            ++c;
        }
    }
    cnt[n] = c;
}

// ---------------- merged weight fragment pre-pack (1 launch) ---------------
#define N_PREP 14
struct PrepArgs {
    const float* w[N_PREP];
    unsigned short* o[N_PREP];
    int cin[N_PREP], cout[N_PREP], cig[N_PREP], mt[N_PREP], base[N_PREP];
};

__global__ __launch_bounds__(64) void k_prep_all(PrepArgs a)
{
    int b = blockIdx.x;
    int L = 0;
    #pragma unroll
    for (int i = 1; i < N_PREP; ++i) if (b >= a.base[i]) L = i;
    int rel = b - a.base[L];
    int MT = a.mt[L], CIG = a.cig[L];
    int m = rel % MT; rel /= MT;
    int cg = rel % CIG;
    int kk = rel / CIG;
    int Cin = a.cin[L], Cout = a.cout[L];
    int lane = threadIdx.x;
    int co = m * 32 + (lane & 31), kg = lane >> 5;
    float v[8];
    #pragma unroll
    for (int j = 0; j < 8; ++j) {
        int ci = cg * 16 + kg * 8 + j;
        v[j] = (co < Cout && ci < Cin) ? a.w[L][((size_t)co * Cin + ci) * 9 + kk] : 0.f;
    }
    *(uint4*)(a.o[L] + ((size_t)((kk * CIG + cg) * MT + m) * 64 + lane) * 8) = pack8(v);
}

// ---------------- k_front: embed + c1 + c2 + c3 fused (8 waves) ------------
__global__ __launch_bounds__(512) void k_front(
    const float* __restrict__ x, const float* __restrict__ t,
    const float* __restrict__ wt, const float* __restrict__ bt,
    const unsigned short* __restrict__ wf1, const float* __restrict__ b1,
    const unsigned short* __restrict__ wf2, const float* __restrict__ b2,
    const unsigned short* __restrict__ wf3, const float* __restrict__ b3,
    bf16* __restrict__ c3o, int node_base)
{
    // chunks: bufA [0,2048), bufB [2048,4096), zero 4096
    __shared__ __align__(16) short lds[4097 * 8];
    __shared__ float s_t[10];
    const int nl = blockIdx.x, n = node_base + nl, tid = threadIdx.x;
    const int wid = tid >> 6, lane = tid & 63;
    if (tid < 10) s_t[tid] = t[n * 10 + tid];
    if (tid < 8)  lds[4096 * 8 + tid] = 0;
    __syncthreads();

    // embed -> bufA (16 ch: x | 8 t-proj | zeros)
    #pragma unroll
    for (int p = 0; p < 2; ++p) {
        int px = tid + p * 512;
        float ch[16];
        ch[0] = x[(size_t)n * 1024 + px];
        #pragma unroll
        for (int c = 1; c <= 8; ++c) {
            int o = (c - 1) * 1024 + px;
            float a = bt[o];
            const float* wr = wt + (size_t)o * 10;
            #pragma unroll
            for (int k = 0; k < 10; ++k) a += wr[k] * s_t[k];
            ch[c] = a;
        }
        #pragma unroll
        for (int c = 9; c < 16; ++c) ch[c] = 0.f;
        *(uint4*)(lds + (size_t)px * 8)          = pack8(ch);
        *(uint4*)(lds + (size_t)(1024 + px) * 8) = pack8(ch + 8);
    }
    __syncthreads();

    f32x16 acc[4];
    // c1: A -> B, relu
    zacc<4>(acc);
    mfma_rr32<4, 8>(lds, 0, 4096, wf1, 512, acc, wid, lane);
    conv_epi<32, 16, 1, 4, 32, 8, false>(lds, 2048, nullptr, b1, acc, wid, lane);
    __syncthreads();
    // c2: B -> A, relu
    zacc<4>(acc);
    mfma_rr32<4, 8>(lds, 2048, 4096, wf2, 512, acc, wid, lane);
    conv_epi<32, 16, 1, 4, 32, 8, false>(lds, 0, nullptr, b2, acc, wid, lane);
    __syncthreads();
    // c3: A -> global, relu
    zacc<4>(acc);
    mfma_rr32<4, 8>(lds, 0, 4096, wf3, 512, acc, wid, lane);
    conv_epi<32, 16, 1, 4, 32, 8, true>(lds, 0,
        (unsigned short*)c3o + (size_t)nl * 16384, b3, acc, wid, lane);
}

// ---------------- k_mid1: m1c1 + m1c2 + m1c3 + ds1 fused (8 waves) ---------
__global__ __launch_bounds__(512) void k_mid1(
    const bf16* __restrict__ c3o, const bf16* __restrict__ g1p,
    const unsigned short* __restrict__ wf1, const float* __restrict__ b1,
    const unsigned short* __restrict__ wf2, const float* __restrict__ b2,
    const unsigned short* __restrict__ wf3, const float* __restrict__ b3,
    const unsigned short* __restrict__ wfd, const float* __restrict__ bd,
    bf16* __restrict__ ds1o)
{
    // chunks: stageA [0,2048), stageB [2048,4096), bufX [4096,8192),
    //         bufY [0,4096) (after m1c1), m1c3-out [4096,6144), zero 8192
    __shared__ __align__(16) short lds[8193 * 8];
    const int nl = blockIdx.x, tid = threadIdx.x;
    const int wid = tid >> 6, lane = tid & 63;
    if (tid < 8) lds[8192 * 8 + tid] = 0;

    uint4* l4 = (uint4*)lds;
    const uint4* s0 = (const uint4*)c3o + (size_t)nl * 2048;
    const uint4* s1 = (const uint4*)g1p + (size_t)nl * 4096;
    const uint4* s2 = s1 + 2048;
    #pragma unroll
    for (int r = 0; r < 4; ++r) l4[tid + r * 512] = s0[tid + r * 512];
    __syncthreads();

    f32x16 acc[4];
    zacc<4>(acc);
    uint4 pf[4];
    // ph0 (self, in A) || prefetch pos -> B
    #pragma unroll
    for (int r = 0; r < 4; ++r) pf[r] = s1[tid + r * 512];
    mfma_rr32<4, 8>(lds, 0, 8192, wf1, 3 * 512, acc, wid, lane);
    #pragma unroll
    for (int r = 0; r < 4; ++r) l4[2048 + tid + r * 512] = pf[r];
    __syncthreads();
    // ph1 (pos, in B) || prefetch neg -> A
    #pragma unroll
    for (int r = 0; r < 4; ++r) pf[r] = s2[tid + r * 512];
    mfma_rr32<4, 8>(lds, 2048, 8192, wf1 + 512, 3 * 512, acc, wid, lane);
    #pragma unroll
    for (int r = 0; r < 4; ++r) l4[tid + r * 512] = pf[r];
    __syncthreads();
    // ph2 (neg, in A)
    mfma_rr32<4, 8>(lds, 0, 8192, wf1 + 1024, 3 * 512, acc, wid, lane);
    conv_epi<32, 32, 0, 4, 32, 8, false>(lds, 4096, nullptr, b1, acc, wid, lane);
    __syncthreads();

    // m1c2: bufX -> bufY
    zacc<4>(acc);
    mfma_rr32<4, 8>(lds, 4096, 8192, wf2,       2 * 512, acc, wid, lane);
    mfma_rr32<4, 8>(lds, 6144, 8192, wf2 + 512, 2 * 512, acc, wid, lane);
    conv_epi<32, 32, 0, 4, 32, 8, false>(lds, 0, nullptr, b2, acc, wid, lane);
    __syncthreads();

    // m1c3: bufY -> [4096,6144)
    zacc<4>(acc);
    mfma_rr32<4, 8>(lds, 0,    8192, wf3,       2 * 512, acc, wid, lane);
    mfma_rr32<4, 8>(lds, 2048, 8192, wf3 + 512, 2 * 512, acc, wid, lane);
    conv_epi<32, 16, 0, 4, 32, 8, false>(lds, 4096, nullptr, b3, acc, wid, lane);
    __syncthreads();

    // ds1: stride-2, relu -> global
    zacc<1>(acc);
    mfma_phase<32, 16, 2, 1, 8, 8>(lds, 4096, 8192, wfd, 512, acc, wid, lane);
    conv_epi<16, 16, 1, 1, 8, 8, true>(lds, 0,
        (unsigned short*)ds1o + (size_t)nl * 4096, bd, acc, wid, lane);
}

// ---------------- k_mid2: m2c1 + m2c2 + m2c3 + ds2 fused (8 waves) ---------
__global__ __launch_bounds__(512) void k_mid2(
    const bf16* __restrict__ ds1o, const bf16* __restrict__ g2p,
    const unsigned short* __restrict__ wf1, const float* __restrict__ b1,
    const unsigned short* __restrict__ wf2, const float* __restrict__ b2,
    const unsigned short* __restrict__ wf3, const float* __restrict__ b3,
    const unsigned short* __restrict__ wfd, const float* __restrict__ bd,
    bf16* __restrict__ ds2o)
{
    // chunks: stageA [0,512), stageB [512,1024), bufX [1024,2048),
    //         bufY [0,1024), m2c3-out [1024,1536), zero 2048
    __shared__ __align__(16) short lds[2049 * 8];
    const int nl = blockIdx.x, tid = threadIdx.x;
    const int wid = tid >> 6, lane = tid & 63;
    if (tid < 8) lds[2048 * 8 + tid] = 0;

    uint4* l4 = (uint4*)lds;
    const uint4* s0 = (const uint4*)ds1o + (size_t)nl * 512;
    const uint4* s1 = (const uint4*)g2p + (size_t)nl * 1024;
    const uint4* s2 = s1 + 512;
    l4[tid] = s0[tid];
    __syncthreads();

    f32x16 acc[1];
    zacc<1>(acc);
    uint4 pf;
    pf = s1[tid];
    mfma_phase<16, 16, 1, 1, 8, 8>(lds, 0, 2048, wf1, 3 * 512, acc, wid, lane);
    l4[512 + tid] = pf;
    __syncthreads();
    pf = s2[tid];
    mfma_phase<16, 16, 1, 1, 8, 8>(lds, 512, 2048, wf1 + 512, 3 * 512, acc, wid, lane);
    l4[tid] = pf;
    __syncthreads();
    mfma_phase<16, 16, 1, 1, 8, 8>(lds, 0, 2048, wf1 + 1024, 3 * 512, acc, wid, lane);
    conv_epi<16, 32, 0, 1, 8, 8, false>(lds, 1024, nullptr, b1, acc, wid, lane);
    __syncthreads();

    zacc<1>(acc);
    mfma_phase<16, 16, 1, 1, 8, 8>(lds, 1024, 2048, wf2,       2 * 512, acc, wid, lane);
    mfma_phase<16, 16, 1, 1, 8, 8>(lds, 1536, 2048, wf2 + 512, 2 * 512, acc, wid, lane);
    conv_epi<16, 32, 0, 1, 8, 8, false>(lds, 0, nullptr, b2, acc, wid, lane);
    __syncthreads();

    zacc<1>(acc);
    mfma_phase<16, 16, 1, 1, 8, 8>(lds, 0,   2048, wf3,       2 * 512, acc, wid, lane);
    mfma_phase<16, 16, 1, 1, 8, 8>(lds, 512, 2048, wf3 + 512, 2 * 512, acc, wid, lane);
    conv_epi<16, 16, 0, 1, 8, 8, false>(lds, 1024, nullptr, b3, acc, wid, lane);
    __syncthreads();

    zacc<1>(acc);
    mfma_phase<16, 8, 2, 1, 2, 8>(lds, 1024, 2048, wfd, 512, acc, wid, lane);
    conv_epi<8, 16, 1, 1, 2, 8, true>(lds, 0,
        (unsigned short*)ds2o + (size_t)nl * 1024, bd, acc, wid, lane);
}

// ---------------- read-once LDS gather: pos/neg sums only ------------------
template<int NPIX>
__global__ __launch_bounds__(256) void k_gather2(
    const bf16* __restrict__ in, const int* __restrict__ cnt,
    const int* __restrict__ lst, bf16* __restrict__ out, int node_base)
{
    constexpr int CPN = 2 * NPIX;
    __shared__ __align__(16) uint4 s_in[16 * 128];
    __shared__ int s_pos[16], s_neg[16];

    const int gl = blockIdx.x, sp = blockIdx.y, tid = threadIdx.x;
    const int gn0 = node_base + gl * 16, nl0 = gl * 16;

    if (tid < 16) {
        int c = cnt[gn0 + tid]; if (c > 16) c = 16;
        int pm = 0, nm = 0;
        for (int k = 0; k < c; ++k) {
            int e = lst[(size_t)(gn0 + tid) * 16 + k];
            int sl = (e & 0x7FFFFFFF) - gn0;
            if ((unsigned)sl < 16u) { if (e < 0) nm |= 1 << sl; else pm |= 1 << sl; }
        }
        s_pos[tid] = pm; s_neg[tid] = nm;
    }
    const uint4* in4 = (const uint4*)in;
    for (int i = tid; i < 2048; i += 256) {
        int srcn = i >> 7, chk = i & 127;
        s_in[i] = in4[(size_t)(nl0 + srcn) * CPN + sp * 128 + chk];
    }
    __syncthreads();

    const int dh = tid >> 7, ch = tid & 127;
    int pm[8], nm[8];
    #pragma unroll
    for (int dl = 0; dl < 8; ++dl) {
        pm[dl] = __builtin_amdgcn_readfirstlane(s_pos[dh * 8 + dl]);
        nm[dl] = __builtin_amdgcn_readfirstlane(s_neg[dh * 8 + dl]);
    }

    float aP[8][8], aN[8][8];
    #pragma unroll
    for (int dl = 0; dl < 8; ++dl)
        #pragma unroll
        for (int j = 0; j < 8; ++j) { aP[dl][j] = 0.f; aN[dl][j] = 0.f; }

    for (int s = 0; s < 16; ++s) {
        union { uint4 v; unsigned short u[8]; } q;
        q.v = s_in[s * 128 + ch];
        float f[8];
        #pragma unroll
        for (int j = 0; j < 8; ++j) f[j] = bf2f(q.u[j]);
        #pragma unroll
        for (int dl = 0; dl < 8; ++dl) {
            if ((pm[dl] >> s) & 1) {
                #pragma unroll
                for (int j = 0; j < 8; ++j) aP[dl][j] += f[j];
            }
            if ((nm[dl] >> s) & 1) {
                #pragma unroll
                for (int j = 0; j < 8; ++j) aN[dl][j] += f[j];
            }
        }
    }

    uint4* out4 = (uint4*)out;
    #pragma unroll
    for (int dl = 0; dl < 8; ++dl) {
        int d = nl0 + dh * 8 + dl;
        out4[((size_t)d * 2 + 0) * CPN + sp * 128 + ch] = pack8(aP[dl]);
        out4[((size_t)d * 2 + 1) * CPN + sp * 128 + ch] = pack8(aN[dl]);
    }
}

// ---------------- MFMA stride-2 conv, images batched into N (d1/d2/d3) -----
template<int HIN, int CIG, int COUT, int IPB, int FUSE_POOL>
__global__ __launch_bounds__(256) void k_tail(
    const bf16* __restrict__ in, const unsigned short* __restrict__ wf,
    const float* __restrict__ bias, bf16* __restrict__ out,
    const int* __restrict__ nd, const float* __restrict__ pw,
    float* __restrict__ pool_out, int nc, int node_base)
{
    constexpr int HOUT = HIN / 2, NPO = HOUT * HOUT, NPI = HIN * HIN;
    constexpr int MT  = (COUT + 31) / 32;
    constexpr int NT  = (IPB * NPO) / 32;
    constexpr int TOT = MT * NT;
    constexpr int TPW = TOT / 4;
    static_assert(TOT % 4 == 0, "tile count must divide over 4 waves");
    constexpr int CHUNKS = IPB * 2 * CIG * NPI;
    __shared__ __align__(16) short sbuf[CHUNKS * 8 + 8];

    const int tid = threadIdx.x, wid = tid >> 6, lane = tid & 63;
    const int col = lane & 31, kg = lane >> 5;
    const int img0 = blockIdx.x * IPB;

    {
        const uint4* src = (const uint4*)in + (size_t)img0 * (2 * CIG * NPI);
        uint4* dst = (uint4*)sbuf;
        int nav = nc - img0; if (nav > IPB) nav = IPB;
        int nch = nav * 2 * CIG * NPI;
        uint4 z = {0, 0, 0, 0};
        for (int i = tid; i < CHUNKS; i += 256) dst[i] = (i < nch) ? src[i] : z;
        if (tid < 8) sbuf[CHUNKS * 8 + tid] = 0;
    }
    __syncthreads();

    int imgb[TPW], poff[TPW][9];
    #pragma unroll
    for (int t = 0; t < TPW; ++t) {
        int tl = wid + 4 * t;
        int n  = tl % NT;
        int idx = n * 32 + col;
        int img = idx / NPO, px = idx % NPO;
        imgb[t] = img * (2 * CIG * NPI);
        int oy = px / HOUT, ox = px % HOUT;
        #pragma unroll
        for (int kk = 0; kk < 9; ++kk) {
            int iy = 2 * oy + kk / 3 - 1, ix = 2 * ox + kk % 3 - 1;
            bool ok = ((unsigned)iy < (unsigned)HIN) && ((unsigned)ix < (unsigned)HIN);
            poff[t][kk] = ok ? (iy * HIN + ix) : -1;
        }
    }

    f32x16 acc[TPW];
    #pragma unroll
    for (int t = 0; t < TPW; ++t)
        #pragma unroll
        for (int e = 0; e < 16; ++e) acc[t][e] = 0.f;

    for (int cig = 0; cig < CIG; ++cig) {
        #pragma unroll
        for (int t = 0; t < TPW; ++t) {
            int m = (wid + 4 * t) / NT;
            #pragma unroll
            for (int kk = 0; kk < 9; ++kk) {
                short8 wfr = *(const short8*)(wf +
                    ((size_t)((kk * CIG + cig) * MT + m) * 64 + lane) * 8);
                int chunk = (poff[t][kk] >= 0)
                          ? imgb[t] + (cig * 2 + kg) * NPI + poff[t][kk]
                          : CHUNKS;
                acc[t] = __builtin_amdgcn_mfma_f32_32x32x16_bf16(
                            wfr, *(const short8*)(sbuf + chunk * 8), acc[t], 0, 0, 0);
            }
        }
    }

    #pragma unroll
    for (int t = 0; t < TPW; ++t) {
        int tl = wid + 4 * t;
        int m = tl / NT, n = tl % NT;
        int idx = n * 32 + col;
        int img = idx / NPO, px = idx % NPO;
        bool live = (img0 + img) < nc;
        if (FUSE_POOL) {
            float part = 0.f;
            #pragma unroll
            for (int r = 0; r < 16; ++r) {
                int co = m * 32 + (r & 3) + 8 * (r >> 2) + 4 * kg;
                float v = acc[t][r] + bias[co];
                v = (v >= 0.f) ? v : 0.1f * v;
                part += v * pw[co];
            }
            part += __shfl_xor(part, 32, 64);
            if (kg == 0 && live) {
                int g = nd[node_base + img0 + img];
                if (g < 0) g = 0; if (g >= N_GRAPHS) g = N_GRAPHS - 1;
                atomicAdd(&pool_out[g], part);
            }
        } else if (live) {
            unsigned short* outp = (unsigned short*)out;
            #pragma unroll
            for (int q = 0; q < 4; ++q) {
                if (m * 32 + q * 8 < COUT) {
                    unsigned short u[4];
                    #pragma unroll
                    for (int j = 0; j < 4; ++j) {
                        int co = m * 32 + q * 8 + kg * 4 + j;
                        float v = acc[t][4 * q + j] + bias[co];
                        v = (v >= 0.f) ? v : 0.1f * v;
                        u[j] = f2bf(v);
                    }
                    uint2 pk;
                    pk.x = u[0] | ((unsigned)u[1] << 16);
                    pk.y = u[2] | ((unsigned)u[3] << 16);
                    *(uint2*)(outp + (((size_t)(img0 + img) * (COUT / 8)
                              + (m * 4 + q)) * NPO + px) * 8 + kg * 4) = pk;
                }
            }
        }
    }
}

// ---------------- head init -------------------------------------------------
__global__ void k_init_out(float* out, const float* __restrict__ pb)
{
    int i = threadIdx.x;
    if (i < N_GRAPHS) out[i] = pb[0];
}

// ---------------------------------------------------------------------------
extern "C" void kernel_launch(void* const* d_in, const int* in_sizes, int n_in,
                              void* d_out, int out_size, void* d_ws, size_t ws_size,
                              hipStream_t stream)
{
    const float* x     = (const float*)d_in[0];
    const float* t     = (const float*)d_in[1];
    const int*   edges = (const int*)d_in[2];
    const int*   nd    = (const int*)d_in[3];
    const float* w_t   = (const float*)d_in[4];
    const float* b_t   = (const float*)d_in[5];
    const float* c1w   = (const float*)d_in[6];
    const float* c1b   = (const float*)d_in[7];
    const float* c2w   = (const float*)d_in[8];
    const float* c2b   = (const float*)d_in[9];
    const float* c3w   = (const float*)d_in[10];
    const float* c3b   = (const float*)d_in[11];
    const float* m1c1w = (const float*)d_in[12];
    const float* m1c1b = (const float*)d_in[13];
    const float* m1c2w = (const float*)d_in[14];
    const float* m1c2b = (const float*)d_in[15];
    const float* m1c3w = (const float*)d_in[16];
    const float* m1c3b = (const float*)d_in[17];
    const float* ds1w  = (const float*)d_in[18];
    const float* ds1b  = (const float*)d_in[19];
    const float* m2c1w = (const float*)d_in[20];
    const float* m2c1b = (const float*)d_in[21];
    const float* m2c2w = (const float*)d_in[22];
    const float* m2c2b = (const float*)d_in[23];
    const float* m2c3w = (const float*)d_in[24];
    const float* m2c3b = (const float*)d_in[25];
    const float* ds2w  = (const float*)d_in[26];
    const float* ds2b  = (const float*)d_in[27];
    const float* d1w   = (const float*)d_in[28];
    const float* d1b   = (const float*)d_in[29];
    const float* d2w   = (const float*)d_in[30];
    const float* d2b   = (const float*)d_in[31];
    const float* d3w   = (const float*)d_in[32];
    const float* d3b   = (const float*)d_in[33];
    const float* pw    = (const float*)d_in[34];
    const float* pb    = (const float*)d_in[35];
    float* out = (float*)d_out;

    uint8_t* ws = (uint8_t*)d_ws;
    int* adj_cnt = (int*)ws;                         // [0, 4K)
    int* adj_lst = (int*)(ws + 4096);                // [4K, 68K)
    #define WF(i)  ((unsigned short*)(ws + (128u << 10) + (size_t)(i) * 32768))
    unsigned short* wt_ds1 = (unsigned short*)(ws + (416u  << 10));
    unsigned short* wt_ds2 = (unsigned short*)(ws + (428u  << 10));
    unsigned short* wt_d1  = (unsigned short*)(ws + (440u  << 10));
    unsigned short* wt_d2  = (unsigned short*)(ws + (512u  << 10));
    unsigned short* wt_d3  = (unsigned short*)(ws + (1088u << 10));

    // ---- adaptive chunking: liveness-packed pool, 120 KiB per node --------
    const size_t RESV = 2ull << 20;
    size_t avail = (ws_size > RESV) ? ws_size - RESV : 0;
    int ncap = (int)(avail / (120 * 1024));
    ncap = (ncap / 16) * 16;
    if (ncap < 16) ncap = 16;
    if (ncap > N_NODES) ncap = N_NODES;
    uint8_t* R = ws + RESV;
    #define NB(off_kb) (R + (size_t)(off_kb) * 1024 * ncap)

    bf16*  c3o  = (bf16*)NB(0);     // [0,32)
    bf16*  g1p  = (bf16*)NB(32);    // [32,96)
    bf16*  ds1o = (bf16*)NB(96);    // [96,104)
    bf16*  g2p  = (bf16*)NB(104);   // [104,120)
    bf16*  ds2o = (bf16*)NB(0);     // [0,2)    (c3o/g1p dead)
    bf16*  d1o  = (bf16*)NB(2);     // [2,10)
    bf16*  d2o  = (bf16*)NB(10);    // [10,11)

    int nE    = in_sizes[2] / 3;
    int per_g = nE / N_GRAPHS;

    k_build_adj<<<(N_NODES + 63) / 64, 64, 0, stream>>>(edges, per_g, adj_cnt, adj_lst);
    k_init_out<<<1, 64, 0, stream>>>(out, pb);

    // merged weight prep (single launch)
    {
        PrepArgs pa;
        const float* wsrc[N_PREP] = { c1w, c2w, c3w, m1c1w, m1c2w, m1c3w,
                                      m2c1w, m2c2w, m2c3w, ds1w, ds2w,
                                      d1w, d2w, d3w };
        unsigned short* wdst[N_PREP] = { WF(0), WF(1), WF(2), WF(3), WF(4), WF(5),
                                         WF(6), WF(7), WF(8), wt_ds1, wt_ds2,
                                         wt_d1, wt_d2, wt_d3 };
        int cin_[N_PREP]  = { 9, 16, 16, 48, 32, 32, 48, 32, 32, 16, 16, 16, 256, 128 };
        int cout_[N_PREP] = { 16, 16, 16, 32, 32, 16, 32, 32, 16, 16, 16, 256, 128, 128 };
        int cig_[N_PREP]  = { 1, 1, 1, 3, 2, 2, 3, 2, 2, 1, 1, 1, 16, 8 };
        int mt_[N_PREP]   = { 1, 1, 1, 1, 1, 1, 1, 1, 1, 1, 1, 8, 4, 4 };
        int total = 0;
        for (int i = 0; i < N_PREP; ++i) {
            pa.w[i] = wsrc[i]; pa.o[i] = wdst[i];
            pa.cin[i] = cin_[i]; pa.cout[i] = cout_[i];
            pa.cig[i] = cig_[i]; pa.mt[i] = mt_[i];
            pa.base[i] = total;
            total += 9 * cig_[i] * mt_[i];
        }
        k_prep_all<<<total, 64, 0, stream>>>(pa);
    }

    for (int nb = 0; nb < N_NODES; nb += ncap) {
        int nc = (N_NODES - nb < ncap) ? (N_NODES - nb) : ncap;
        int ng = nc / 16;

        k_front<<<nc, 512, 0, stream>>>(x, t, w_t, b_t,
            WF(0), c1b, WF(1), c2b, WF(2), c3b, c3o, nb);

        k_gather2<1024><<<dim3(ng, 16), 256, 0, stream>>>(c3o, adj_cnt, adj_lst, g1p, nb);

        k_mid1<<<nc, 512, 0, stream>>>(c3o, g1p,
            WF(3), m1c1b, WF(4), m1c2b, WF(5), m1c3b, wt_ds1, ds1b, ds1o);

        k_gather2<256><<<dim3(ng, 4), 256, 0, stream>>>(ds1o, adj_cnt, adj_lst, g2p, nb);

        k_mid2<<<nc, 512, 0, stream>>>(ds1o, g2p,
            WF(6), m2c1b, WF(7), m2c2b, WF(8), m2c3b, wt_ds2, ds2b, ds2o);

        k_tail<8, 1, 256, 4, 0><<<(nc + 3) / 4, 256, 0, stream>>>(
            ds2o, wt_d1, d1b, d1o, nullptr, nullptr, nullptr, nc, nb);
        k_tail<4, 16, 128, 8, 0><<<(nc + 7) / 8, 256, 0, stream>>>(
            d1o, wt_d2, d2b, d2o, nullptr, nullptr, nullptr, nc, nb);
        k_tail<2, 8, 128, 32, 1><<<(nc + 31) / 32, 256, 0, stream>>>(
            d2o, wt_d3, d3b, nullptr, nd, pw, out, nc, nb);
    }
    #undef NB
    #undef WF
}